// Round 7
// baseline (516.698 us; speedup 1.0000x reference)
//
#include <hip/hip_runtime.h>

#define MSG 64
#define NCOMBO 476        // 119 atom ids * 4 bond ids
#define SLICE_SHIFT 10    // 1024 nodes per slice
#define MAXSLICES 128

typedef _Float16 h4 __attribute__((ext_vector_type(4)));

__device__ inline h4 relu4(h4 v) {
    h4 z = {};
    return __builtin_elementwise_max(v, z);
}

// tAB[c][i] = bias[i] + atom[c>>2] @ W[0:64] + bond[c&3] @ W[64:80]   (W ld=64), fp16 out
__global__ void build_tab_kernel(const float* __restrict__ atom, const float* __restrict__ bond,
                                 const float* __restrict__ W, const float* __restrict__ bias,
                                 _Float16* __restrict__ tAB) {
    int t = blockIdx.x * blockDim.x + threadIdx.x;
    if (t >= NCOMBO * MSG) return;
    int i = t & 63, c = t >> 6, xa = c >> 2, ea = c & 3;
    float s = bias[i];
    for (int k = 0; k < 64; ++k) s = fmaf(atom[xa * 64 + k], W[k * 64 + i], s);
    for (int k = 0; k < 16; ++k) s = fmaf(bond[ea * 16 + k], W[(64 + k) * 64 + i], s);
    tAB[t] = (_Float16)s;
}

__global__ void hist_kernel(const int* __restrict__ ei, int E, int* __restrict__ cnt) {
    int e = blockIdx.x * blockDim.x + threadIdx.x;
    if (e < E) atomicAdd(&cnt[ei[E + e]], 1);
}

// block-level inclusive scan (1024/block) + block sums
__global__ void scan1_kernel(const int* __restrict__ cnt, int* __restrict__ incl,
                             int* __restrict__ bsum, int N) {
    int i = blockIdx.x * 1024 + threadIdx.x;
    int v = (i < N) ? cnt[i] : 0;
    int lane = threadIdx.x & 63, w = threadIdx.x >> 6;
    int s = v;
    for (int off = 1; off < 64; off <<= 1) { int t = __shfl_up(s, off); if (lane >= off) s += t; }
    __shared__ int wsum[16];
    if (lane == 63) wsum[w] = s;
    __syncthreads();
    if (w == 0 && lane < 16) {
        int t = wsum[lane];
        for (int off = 1; off < 16; off <<= 1) { int u = __shfl_up(t, off); if (lane >= off) t += u; }
        wsum[lane] = t;
    }
    __syncthreads();
    if (w > 0) s += wsum[w - 1];
    if (i < N) incl[i] = s;
    if (threadIdx.x == 1023) bsum[blockIdx.x] = s;
}

__global__ void scan2_kernel(int* __restrict__ bsum, int nb) {
    if (threadIdx.x == 0 && blockIdx.x == 0) {
        int run = 0;
        for (int b = 0; b < nb; ++b) { int t = bsum[b]; bsum[b] = run; run += t; }
    }
}

__global__ void scan3_kernel(const int* __restrict__ incl, const int* __restrict__ bsum,
                             int* __restrict__ off, int N) {
    int i = blockIdx.x * 1024 + threadIdx.x;
    if (i < N) off[i + 1] = incl[i] + bsum[blockIdx.x];
    if (i == 0) off[0] = 0;
}

__global__ void binit_kernel(const int* __restrict__ offs, int* __restrict__ gcur, int K, int N) {
    int s = blockIdx.x * blockDim.x + threadIdx.x;
    if (s < K) gcur[s] = offs[min(s << SLICE_SHIFT, N)];
}

// Phase 1: radix-partition edges into dst-slices. Block-local LDS ranking, one
// global atomic per (block,slice) for run reservation, near-contiguous 8B writes.
// record = pw(26b)<<17 | dst(17b), pw = src | combo<<17.
__global__ __launch_bounds__(256) void partition_kernel(
    const int* __restrict__ ei, const int* __restrict__ x, const int* __restrict__ eattr,
    int E, int* __restrict__ gcur, unsigned long long* __restrict__ aux, int K)
{
    __shared__ int cnt[MAXSLICES];
    __shared__ int base[MAXSLICES];
    if (threadIdx.x < MAXSLICES) cnt[threadIdx.x] = 0;
    __syncthreads();
    int e0 = blockIdx.x * 1024;
    int sl0 = -1, sl1 = -1, sl2 = -1, sl3 = -1;
    int rk0 = 0, rk1 = 0, rk2 = 0, rk3 = 0;
    unsigned long long p0 = 0, p1 = 0, p2 = 0, p3 = 0;
    {
        int e = e0 + 0 * 256 + threadIdx.x;
        if (e < E) {
            int s = ei[e], d = ei[E + e];
            p0 = ((unsigned long long)((unsigned)s | ((unsigned)(x[s] * 4 + eattr[e]) << 17)) << 17) | (unsigned)d;
            sl0 = d >> SLICE_SHIFT; rk0 = atomicAdd(&cnt[sl0], 1);
        }
    }
    {
        int e = e0 + 1 * 256 + threadIdx.x;
        if (e < E) {
            int s = ei[e], d = ei[E + e];
            p1 = ((unsigned long long)((unsigned)s | ((unsigned)(x[s] * 4 + eattr[e]) << 17)) << 17) | (unsigned)d;
            sl1 = d >> SLICE_SHIFT; rk1 = atomicAdd(&cnt[sl1], 1);
        }
    }
    {
        int e = e0 + 2 * 256 + threadIdx.x;
        if (e < E) {
            int s = ei[e], d = ei[E + e];
            p2 = ((unsigned long long)((unsigned)s | ((unsigned)(x[s] * 4 + eattr[e]) << 17)) << 17) | (unsigned)d;
            sl2 = d >> SLICE_SHIFT; rk2 = atomicAdd(&cnt[sl2], 1);
        }
    }
    {
        int e = e0 + 3 * 256 + threadIdx.x;
        if (e < E) {
            int s = ei[e], d = ei[E + e];
            p3 = ((unsigned long long)((unsigned)s | ((unsigned)(x[s] * 4 + eattr[e]) << 17)) << 17) | (unsigned)d;
            sl3 = d >> SLICE_SHIFT; rk3 = atomicAdd(&cnt[sl3], 1);
        }
    }
    __syncthreads();
    if (threadIdx.x < K && cnt[threadIdx.x] > 0)
        base[threadIdx.x] = atomicAdd(&gcur[threadIdx.x], cnt[threadIdx.x]);
    __syncthreads();
    if (sl0 >= 0) aux[base[sl0] + rk0] = p0;
    if (sl1 >= 0) aux[base[sl1] + rk1] = p1;
    if (sl2 >= 0) aux[base[sl2] + rk2] = p2;
    if (sl3 >= 0) aux[base[sl3] + rk3] = p3;
}

// Phase 2: one block OWNS one slice -> all writes to its 64KB packed window come
// from one CU (one XCD's L2): full lines, single writeback. LDS node cursors.
__global__ __launch_bounds__(1024) void place_kernel(
    const unsigned long long* __restrict__ aux, const int* __restrict__ offs,
    unsigned* __restrict__ packed, int N)
{
    __shared__ int lcur[1 << SLICE_SHIFT];
    int lo = blockIdx.x << SLICE_SHIFT;
    int hi = min(lo + (1 << SLICE_SHIFT), N);
    if (lo + (int)threadIdx.x < hi) lcur[threadIdx.x] = offs[lo + threadIdx.x];
    __syncthreads();
    int start = offs[lo], end = offs[hi];
    for (int idx = start + threadIdx.x; idx < end; idx += 1024) {
        unsigned long long a = aux[idx];
        int d = (int)(a & 0x1FFFFu);
        unsigned pw = (unsigned)(a >> 17);
        int p = atomicAdd(&lcur[d & ((1 << SLICE_SHIFT) - 1)], 1);
        packed[p] = pw;
    }
}

// 16 lanes per node (h4 per lane), 16 nodes per 256-thread block.
// acc = sum_{in-edges} relu(tAB[combo] + agg2[src]), packed-fp16 math (v_pk_*).
// MODE 0: no agg2, fused epilogue GEMM; 1: agg2 + fused GEMM; 3: agg2 + atomic mol pool.
template <int MODE>
__global__ __launch_bounds__(256) void gather_kernel(
    const unsigned* __restrict__ packed, const int* __restrict__ off,
    const _Float16* __restrict__ tAB, const _Float16* __restrict__ agg2,
    const float* __restrict__ Wagg, const int* __restrict__ batch,
    _Float16* __restrict__ out, float* __restrict__ mol, int N)
{
    __shared__ float Ws[64 * 64];
    __shared__ float rowbuf[16][68];
    if (MODE != 3)
        for (int idx = threadIdx.x; idx < 64 * 64; idx += 256) Ws[idx] = Wagg[idx];
    int t = blockIdx.x * 256 + threadIdx.x;
    int v = t >> 4;                    // node
    int j = threadIdx.x & 15;          // feature quad
    int w = threadIdx.x >> 4;          // group in block
    const h4* tAB4 = (const h4*)tAB;
    const h4* agg4 = (const h4*)agg2;
    h4 acc = {};
    if (v < N) {
        int e = off[v], end = off[v + 1];
        for (; e + 7 < end; e += 8) {
            unsigned q0 = packed[e], q1 = packed[e + 1], q2 = packed[e + 2], q3 = packed[e + 3];
            unsigned q4 = packed[e + 4], q5 = packed[e + 5], q6 = packed[e + 6], q7 = packed[e + 7];
            h4 m0 = tAB4[(q0 >> 17) * 16 + j];
            h4 m1 = tAB4[(q1 >> 17) * 16 + j];
            h4 m2 = tAB4[(q2 >> 17) * 16 + j];
            h4 m3 = tAB4[(q3 >> 17) * 16 + j];
            h4 m4 = tAB4[(q4 >> 17) * 16 + j];
            h4 m5 = tAB4[(q5 >> 17) * 16 + j];
            h4 m6 = tAB4[(q6 >> 17) * 16 + j];
            h4 m7 = tAB4[(q7 >> 17) * 16 + j];
            if (MODE) {
                m0 += agg4[(q0 & 0x1FFFFu) * 16 + j];
                m1 += agg4[(q1 & 0x1FFFFu) * 16 + j];
                m2 += agg4[(q2 & 0x1FFFFu) * 16 + j];
                m3 += agg4[(q3 & 0x1FFFFu) * 16 + j];
                m4 += agg4[(q4 & 0x1FFFFu) * 16 + j];
                m5 += agg4[(q5 & 0x1FFFFu) * 16 + j];
                m6 += agg4[(q6 & 0x1FFFFu) * 16 + j];
                m7 += agg4[(q7 & 0x1FFFFu) * 16 + j];
            }
            h4 s01 = relu4(m0) + relu4(m1);
            h4 s23 = relu4(m2) + relu4(m3);
            h4 s45 = relu4(m4) + relu4(m5);
            h4 s67 = relu4(m6) + relu4(m7);
            acc += (s01 + s23) + (s45 + s67);
        }
        for (; e < end; ++e) {
            unsigned q0 = packed[e];
            h4 m0 = tAB4[(q0 >> 17) * 16 + j];
            if (MODE) m0 += agg4[(q0 & 0x1FFFFu) * 16 + j];
            acc += relu4(m0);
        }
    }
    float ax = (float)acc.x, ay = (float)acc.y, az = (float)acc.z, aw = (float)acc.w;
    if (MODE == 3) {
        if (v < N) {
            float* mp = &mol[(long long)batch[v] * 64 + j * 4];
            atomicAdd(mp + 0, ax); atomicAdd(mp + 1, ay);
            atomicAdd(mp + 2, az); atomicAdd(mp + 3, aw);
        }
        return;
    }
    rowbuf[w][j * 4 + 0] = ax;
    rowbuf[w][j * 4 + 1] = ay;
    rowbuf[w][j * 4 + 2] = az;
    rowbuf[w][j * 4 + 3] = aw;
    __syncthreads();
    if (v >= N) return;
    const float4* Ws4 = (const float4*)Ws;
    float sx = 0.f, sy = 0.f, sz = 0.f, sw = 0.f;
#pragma unroll
    for (int k = 0; k < 64; ++k) {
        float r = rowbuf[w][k];
        float4 wv = Ws4[k * 16 + j];
        sx = fmaf(r, wv.x, sx);
        sy = fmaf(r, wv.y, sy);
        sz = fmaf(r, wv.z, sz);
        sw = fmaf(r, wv.w, sw);
    }
    h4 o; o.x = (_Float16)sx; o.y = (_Float16)sy; o.z = (_Float16)sz; o.w = (_Float16)sw;
    ((h4*)out)[(long long)v * 16 + j] = o;
}

__global__ void head_kernel(const float* __restrict__ mol, const float* __restrict__ W1,
                            const float* __restrict__ b1, const float* __restrict__ W2,
                            const float* __restrict__ b2, float* __restrict__ out) {
    int g = blockIdx.x;
    int j = threadIdx.x;   // 0..127
    float s = b1[j];
#pragma unroll
    for (int k = 0; k < 64; ++k) s = fmaf(mol[g * 64 + k], W1[k * 128 + j], s);
    s = fmaxf(s, 0.0f) * W2[j];
    __shared__ float red[128];
    red[j] = s;
    __syncthreads();
    for (int off = 64; off > 0; off >>= 1) {
        if (j < off) red[j] += red[j + off];
        __syncthreads();
    }
    if (j == 0) out[g] = red[0] + b2[0];
}

extern "C" void kernel_launch(void* const* d_in, const int* in_sizes, int n_in,
                              void* d_out, int out_size, void* d_ws, size_t ws_size,
                              hipStream_t stream) {
    const int*   x          = (const int*)d_in[0];
    const int*   eattr      = (const int*)d_in[1];
    const int*   ei         = (const int*)d_in[2];
    const int*   batch      = (const int*)d_in[3];
    const float* atom_table = (const float*)d_in[4];
    const float* bond_table = (const float*)d_in[5];
    const float* Wi         = (const float*)d_in[6];
    const float* bi         = (const float*)d_in[7];
    const float* Wu         = (const float*)d_in[8];
    const float* bu         = (const float*)d_in[9];
    const float* W1         = (const float*)d_in[10];
    const float* b1         = (const float*)d_in[11];
    const float* W2         = (const float*)d_in[12];
    const float* b2         = (const float*)d_in[13];

    const int N = in_sizes[0];      // 100000
    const int E = in_sizes[1];      // 1600000
    const int M = out_size;         // 2048
    const int K = (N + (1 << SLICE_SHIFT) - 1) >> SLICE_SHIFT;   // 98 slices

    char* ws = (char*)d_ws;
    size_t off_b = 0;
    auto alloc = [&](size_t bytes) -> void* {
        void* p = ws + off_b;
        off_b = (off_b + bytes + 255) & ~(size_t)255;
        return p;
    };
    _Float16* bufA  = (_Float16*)alloc((size_t)N * MSG * 2);
    _Float16* bufB  = (_Float16*)alloc((size_t)N * MSG * 2);
    unsigned* packed = (unsigned*)alloc((size_t)E * 4);
    unsigned long long* aux = (unsigned long long*)alloc((size_t)E * 8);
    int*      cnt    = (int*)alloc((size_t)N * 4);
    int*      incl   = (int*)alloc((size_t)N * 4);
    int*      offs   = (int*)alloc((size_t)(N + 1) * 4);
    int*      gcur   = (int*)alloc((size_t)MAXSLICES * 4);
    int*      bsum   = (int*)alloc(1024 * 4);
    _Float16* tABi   = (_Float16*)alloc((size_t)NCOMBO * MSG * 2);
    _Float16* tABu   = (_Float16*)alloc((size_t)NCOMBO * MSG * 2);
    float*    mol    = (float*)alloc((size_t)M * MSG * 4);
    (void)ws_size; (void)n_in;

    // Combined tables (atom@W + bond@W + bias), one row per (x, eattr) combo.
    build_tab_kernel<<<(NCOMBO * MSG + 255) / 256, 256, 0, stream>>>(atom_table, bond_table, Wi, bi, tABi);
    build_tab_kernel<<<(NCOMBO * MSG + 255) / 256, 256, 0, stream>>>(atom_table, bond_table, Wu, bu, tABu);

    // ---- CSR by dst: hist+scan -> offs; radix partition -> aux; place -> packed ----
    const int nb = (N + 1023) / 1024;
    hipMemsetAsync(cnt, 0, (size_t)N * 4, stream);
    hist_kernel<<<(E + 255) / 256, 256, 0, stream>>>(ei, E, cnt);
    scan1_kernel<<<nb, 1024, 0, stream>>>(cnt, incl, bsum, N);
    scan2_kernel<<<1, 64, 0, stream>>>(bsum, nb);
    scan3_kernel<<<nb, 1024, 0, stream>>>(incl, bsum, offs, N);
    binit_kernel<<<1, MAXSLICES, 0, stream>>>(offs, gcur, K, N);
    partition_kernel<<<(E + 1023) / 1024, 256, 0, stream>>>(ei, x, eattr, E, gcur, aux, K);
    place_kernel<<<K, 1024, 0, stream>>>(aux, offs, packed, N);

    // ---- message passes (gather form, fused node-GEMM epilogue, pk-f16 math) ----
    const int gblocks = (int)(((long long)N * 16 + 255) / 256);
    const float* Wagg = Wu + 80 * MSG;
    hipMemsetAsync(mol, 0, (size_t)M * MSG * 4, stream);
    gather_kernel<0><<<gblocks, 256, 0, stream>>>(packed, offs, tABi, nullptr, Wagg, batch, bufA, nullptr, N);
    gather_kernel<1><<<gblocks, 256, 0, stream>>>(packed, offs, tABu, bufA, Wagg, batch, bufB, nullptr, N);
    gather_kernel<1><<<gblocks, 256, 0, stream>>>(packed, offs, tABu, bufB, Wagg, batch, bufA, nullptr, N);
    gather_kernel<1><<<gblocks, 256, 0, stream>>>(packed, offs, tABu, bufA, Wagg, batch, bufB, nullptr, N);
    gather_kernel<3><<<gblocks, 256, 0, stream>>>(packed, offs, tABu, bufB, Wagg, batch, nullptr, mol, N);

    // ---- readout ----
    head_kernel<<<M, 128, 0, stream>>>(mol, W1, b1, W2, b2, (float*)d_out);
}

// Round 8
// 431.234 us; speedup vs baseline: 1.1982x; 1.1982x over previous
//
#include <hip/hip_runtime.h>

#define MSG 64
#define SLICE_SHIFT 10    // 1024 nodes per slice
#define MAXSLICES 128

typedef _Float16 h4 __attribute__((ext_vector_type(4)));

__device__ inline h4 relu4(h4 v) {
    h4 z = {};
    return __builtin_elementwise_max(v, z);
}

// tA[a][i] = atom[a] @ W[0:64]   (W ld=64), fp16 out
__global__ void build_tabA_kernel(const float* __restrict__ atom, const float* __restrict__ W,
                                  _Float16* __restrict__ tA, int rows) {
    int t = blockIdx.x * blockDim.x + threadIdx.x;
    if (t >= rows * MSG) return;
    int i = t & 63, a = t >> 6;
    float s = 0.f;
    for (int k = 0; k < 64; ++k) s = fmaf(atom[a * 64 + k], W[k * 64 + i], s);
    tA[t] = (_Float16)s;
}

// tB[b][i] = bias[i] + bond[b] @ W[64:80]   (W16 = W + 64*64), fp16 out. 4 rows.
__global__ void build_tabB_kernel(const float* __restrict__ bond, const float* __restrict__ W16,
                                  const float* __restrict__ bias, _Float16* __restrict__ tB) {
    int t = threadIdx.x;    // 256 = 4 rows * 64
    int i = t & 63, b = t >> 6;
    float s = bias[i];
    for (int k = 0; k < 16; ++k) s = fmaf(bond[b * 16 + k], W16[k * 64 + i], s);
    tB[t] = (_Float16)s;
}

// bufC[v] = tAi[x[v]]  (node-level atom-term table for pass 0)
__global__ void node_init_kernel(const int* __restrict__ x, const _Float16* __restrict__ tA,
                                 _Float16* __restrict__ bufC, int N) {
    int t = blockIdx.x * blockDim.x + threadIdx.x;
    int v = t >> 4, j = t & 15;
    if (v < N) ((h4*)bufC)[(long long)v * 16 + j] = ((const h4*)tA)[x[v] * 16 + j];
}

__global__ void hist_kernel(const int* __restrict__ ei, int E, int* __restrict__ cnt) {
    int e = blockIdx.x * blockDim.x + threadIdx.x;
    if (e < E) atomicAdd(&cnt[ei[E + e]], 1);
}

// block-level inclusive scan (1024/block) + block sums
__global__ void scan1_kernel(const int* __restrict__ cnt, int* __restrict__ incl,
                             int* __restrict__ bsum, int N) {
    int i = blockIdx.x * 1024 + threadIdx.x;
    int v = (i < N) ? cnt[i] : 0;
    int lane = threadIdx.x & 63, w = threadIdx.x >> 6;
    int s = v;
    for (int off = 1; off < 64; off <<= 1) { int t = __shfl_up(s, off); if (lane >= off) s += t; }
    __shared__ int wsum[16];
    if (lane == 63) wsum[w] = s;
    __syncthreads();
    if (w == 0 && lane < 16) {
        int t = wsum[lane];
        for (int off = 1; off < 16; off <<= 1) { int u = __shfl_up(t, off); if (lane >= off) t += u; }
        wsum[lane] = t;
    }
    __syncthreads();
    if (w > 0) s += wsum[w - 1];
    if (i < N) incl[i] = s;
    if (threadIdx.x == 1023) bsum[blockIdx.x] = s;
}

__global__ void scan2_kernel(int* __restrict__ bsum, int nb) {
    if (threadIdx.x == 0 && blockIdx.x == 0) {
        int run = 0;
        for (int b = 0; b < nb; ++b) { int t = bsum[b]; bsum[b] = run; run += t; }
    }
}

__global__ void scan3_kernel(const int* __restrict__ incl, const int* __restrict__ bsum,
                             int* __restrict__ off, int N) {
    int i = blockIdx.x * 1024 + threadIdx.x;
    if (i < N) off[i + 1] = incl[i] + bsum[blockIdx.x];
    if (i == 0) off[0] = 0;
}

__global__ void binit_kernel(const int* __restrict__ offs, int* __restrict__ gcur, int K, int N) {
    int s = blockIdx.x * blockDim.x + threadIdx.x;
    if (s < K) gcur[s] = offs[min(s << SLICE_SHIFT, N)];
}

// Phase 1: radix-partition edges into dst-slices. Block-local LDS ranking, one
// global atomic per (block,slice), near-contiguous 8B writes.
// record = pw(19b)<<17 | dst(17b), pw = src | eattr<<17.
__global__ __launch_bounds__(256) void partition_kernel(
    const int* __restrict__ ei, const int* __restrict__ eattr,
    int E, int* __restrict__ gcur, unsigned long long* __restrict__ aux, int K)
{
    __shared__ int cnt[MAXSLICES];
    __shared__ int base[MAXSLICES];
    if (threadIdx.x < MAXSLICES) cnt[threadIdx.x] = 0;
    __syncthreads();
    int e0 = blockIdx.x * 1024;
    int sl0 = -1, sl1 = -1, sl2 = -1, sl3 = -1;
    int rk0 = 0, rk1 = 0, rk2 = 0, rk3 = 0;
    unsigned long long p0 = 0, p1 = 0, p2 = 0, p3 = 0;
    {
        int e = e0 + 0 * 256 + threadIdx.x;
        if (e < E) {
            int s = ei[e], d = ei[E + e];
            p0 = ((unsigned long long)((unsigned)s | ((unsigned)eattr[e] << 17)) << 17) | (unsigned)d;
            sl0 = d >> SLICE_SHIFT; rk0 = atomicAdd(&cnt[sl0], 1);
        }
    }
    {
        int e = e0 + 1 * 256 + threadIdx.x;
        if (e < E) {
            int s = ei[e], d = ei[E + e];
            p1 = ((unsigned long long)((unsigned)s | ((unsigned)eattr[e] << 17)) << 17) | (unsigned)d;
            sl1 = d >> SLICE_SHIFT; rk1 = atomicAdd(&cnt[sl1], 1);
        }
    }
    {
        int e = e0 + 2 * 256 + threadIdx.x;
        if (e < E) {
            int s = ei[e], d = ei[E + e];
            p2 = ((unsigned long long)((unsigned)s | ((unsigned)eattr[e] << 17)) << 17) | (unsigned)d;
            sl2 = d >> SLICE_SHIFT; rk2 = atomicAdd(&cnt[sl2], 1);
        }
    }
    {
        int e = e0 + 3 * 256 + threadIdx.x;
        if (e < E) {
            int s = ei[e], d = ei[E + e];
            p3 = ((unsigned long long)((unsigned)s | ((unsigned)eattr[e] << 17)) << 17) | (unsigned)d;
            sl3 = d >> SLICE_SHIFT; rk3 = atomicAdd(&cnt[sl3], 1);
        }
    }
    __syncthreads();
    if (threadIdx.x < K && cnt[threadIdx.x] > 0)
        base[threadIdx.x] = atomicAdd(&gcur[threadIdx.x], cnt[threadIdx.x]);
    __syncthreads();
    if (sl0 >= 0) aux[base[sl0] + rk0] = p0;
    if (sl1 >= 0) aux[base[sl1] + rk1] = p1;
    if (sl2 >= 0) aux[base[sl2] + rk2] = p2;
    if (sl3 >= 0) aux[base[sl3] + rk3] = p3;
}

// Phase 2: one block OWNS one slice -> all writes to its 64KB packed window come
// from one CU (one XCD's L2): full lines, single writeback. LDS node cursors.
__global__ __launch_bounds__(1024) void place_kernel(
    const unsigned long long* __restrict__ aux, const int* __restrict__ offs,
    unsigned* __restrict__ packed, int N)
{
    __shared__ int lcur[1 << SLICE_SHIFT];
    int lo = blockIdx.x << SLICE_SHIFT;
    int hi = min(lo + (1 << SLICE_SHIFT), N);
    if (lo + (int)threadIdx.x < hi) lcur[threadIdx.x] = offs[lo + threadIdx.x];
    __syncthreads();
    int start = offs[lo], end = offs[hi];
    for (int idx = start + threadIdx.x; idx < end; idx += 1024) {
        unsigned long long a = aux[idx];
        int d = (int)(a & 0x1FFFFu);
        unsigned pw = (unsigned)(a >> 17);
        int p = atomicAdd(&lcur[d & ((1 << SLICE_SHIFT) - 1)], 1);
        packed[p] = pw;
    }
}

// 16 lanes per node (h4 per lane), 16 nodes per 256-thread block.
// acc = sum_{in-edges} relu(nodearr[src] + tB[ea]); tB's 4 rows held in REGISTERS
// (cndmask select, no runtime-indexed array). Single random row-gather per edge.
// !FINAL epilogue: out[v] = (acc @ Wagg) + tAu[x[v]]   (= next pass's nodearr)
// FINAL: out[v] = acc (node_state, fp16).
template <bool FINAL>
__global__ __launch_bounds__(256) void gather_kernel(
    const unsigned* __restrict__ packed, const int* __restrict__ off,
    const _Float16* __restrict__ nodearr, const _Float16* __restrict__ tB,
    const float* __restrict__ Wagg, const _Float16* __restrict__ tAu,
    const int* __restrict__ x, _Float16* __restrict__ out, int N)
{
    __shared__ float Ws[64 * 64];
    __shared__ float rowbuf[16][68];
    if (!FINAL)
        for (int idx = threadIdx.x; idx < 64 * 64; idx += 256) Ws[idx] = Wagg[idx];
    int t = blockIdx.x * 256 + threadIdx.x;
    int v = t >> 4;                    // node
    int j = threadIdx.x & 15;          // feature quad
    int w = threadIdx.x >> 4;          // group in block
    const h4* na4 = (const h4*)nodearr;
    const h4* tB4 = (const h4*)tB;
    h4 tb0 = tB4[0 * 16 + j], tb1 = tB4[1 * 16 + j];
    h4 tb2 = tB4[2 * 16 + j], tb3 = tB4[3 * 16 + j];
    h4 acc = {};
    if (v < N) {
        int e = off[v], end = off[v + 1];
        for (; e + 7 < end; e += 8) {
            unsigned q0 = packed[e],     q1 = packed[e + 1], q2 = packed[e + 2], q3 = packed[e + 3];
            unsigned q4 = packed[e + 4], q5 = packed[e + 5], q6 = packed[e + 6], q7 = packed[e + 7];
            h4 m0 = na4[(q0 & 0x1FFFFu) * 16 + j];
            h4 m1 = na4[(q1 & 0x1FFFFu) * 16 + j];
            h4 m2 = na4[(q2 & 0x1FFFFu) * 16 + j];
            h4 m3 = na4[(q3 & 0x1FFFFu) * 16 + j];
            h4 m4 = na4[(q4 & 0x1FFFFu) * 16 + j];
            h4 m5 = na4[(q5 & 0x1FFFFu) * 16 + j];
            h4 m6 = na4[(q6 & 0x1FFFFu) * 16 + j];
            h4 m7 = na4[(q7 & 0x1FFFFu) * 16 + j];
            unsigned a0 = q0 >> 17, a1 = q1 >> 17, a2 = q2 >> 17, a3 = q3 >> 17;
            unsigned a4 = q4 >> 17, a5 = q5 >> 17, a6 = q6 >> 17, a7 = q7 >> 17;
            h4 s0 = relu4(m0 + ((a0 & 2) ? ((a0 & 1) ? tb3 : tb2) : ((a0 & 1) ? tb1 : tb0)));
            h4 s1 = relu4(m1 + ((a1 & 2) ? ((a1 & 1) ? tb3 : tb2) : ((a1 & 1) ? tb1 : tb0)));
            h4 s2 = relu4(m2 + ((a2 & 2) ? ((a2 & 1) ? tb3 : tb2) : ((a2 & 1) ? tb1 : tb0)));
            h4 s3 = relu4(m3 + ((a3 & 2) ? ((a3 & 1) ? tb3 : tb2) : ((a3 & 1) ? tb1 : tb0)));
            h4 s4 = relu4(m4 + ((a4 & 2) ? ((a4 & 1) ? tb3 : tb2) : ((a4 & 1) ? tb1 : tb0)));
            h4 s5 = relu4(m5 + ((a5 & 2) ? ((a5 & 1) ? tb3 : tb2) : ((a5 & 1) ? tb1 : tb0)));
            h4 s6 = relu4(m6 + ((a6 & 2) ? ((a6 & 1) ? tb3 : tb2) : ((a6 & 1) ? tb1 : tb0)));
            h4 s7 = relu4(m7 + ((a7 & 2) ? ((a7 & 1) ? tb3 : tb2) : ((a7 & 1) ? tb1 : tb0)));
            acc += ((s0 + s1) + (s2 + s3)) + ((s4 + s5) + (s6 + s7));
        }
        for (; e < end; ++e) {
            unsigned q0 = packed[e];
            h4 m0 = na4[(q0 & 0x1FFFFu) * 16 + j];
            unsigned a0 = q0 >> 17;
            acc += relu4(m0 + ((a0 & 2) ? ((a0 & 1) ? tb3 : tb2) : ((a0 & 1) ? tb1 : tb0)));
        }
    }
    if (FINAL) {
        if (v < N) ((h4*)out)[(long long)v * 16 + j] = acc;
        return;
    }
    rowbuf[w][j * 4 + 0] = (float)acc.x;
    rowbuf[w][j * 4 + 1] = (float)acc.y;
    rowbuf[w][j * 4 + 2] = (float)acc.z;
    rowbuf[w][j * 4 + 3] = (float)acc.w;
    __syncthreads();
    if (v >= N) return;
    const float4* Ws4 = (const float4*)Ws;
    float sx = 0.f, sy = 0.f, sz = 0.f, sw = 0.f;
#pragma unroll
    for (int k = 0; k < 64; ++k) {
        float r = rowbuf[w][k];
        float4 wv = Ws4[k * 16 + j];
        sx = fmaf(r, wv.x, sx);
        sy = fmaf(r, wv.y, sy);
        sz = fmaf(r, wv.z, sz);
        sw = fmaf(r, wv.w, sw);
    }
    h4 ta = ((const h4*)tAu)[x[v] * 16 + j];
    sx += (float)ta.x; sy += (float)ta.y; sz += (float)ta.z; sw += (float)ta.w;
    h4 o; o.x = (_Float16)sx; o.y = (_Float16)sy; o.z = (_Float16)sz; o.w = (_Float16)sw;
    ((h4*)out)[(long long)v * 16 + j] = o;
}

// batch is sorted: run-length accumulate, flush on mol change. 16 lanes x h4 per 32-node chunk.
__global__ void mol_pool_kernel(const _Float16* __restrict__ ns, const int* __restrict__ batch,
                                float* __restrict__ mol, int N) {
    int g = (blockIdx.x * blockDim.x + threadIdx.x) >> 4;
    int j = threadIdx.x & 15;
    int n0 = g * 32;
    if (n0 >= N) return;
    int n1 = min(n0 + 32, N);
    const h4* ns4 = (const h4*)ns;
    int cur = batch[n0];
    float ax = 0.f, ay = 0.f, az = 0.f, aw = 0.f;
    for (int n = n0; n < n1; ++n) {
        int b = batch[n];
        if (b != cur) {
            float* mp = &mol[(long long)cur * 64 + j * 4];
            atomicAdd(mp + 0, ax); atomicAdd(mp + 1, ay);
            atomicAdd(mp + 2, az); atomicAdd(mp + 3, aw);
            ax = ay = az = aw = 0.f; cur = b;
        }
        h4 vv = ns4[(long long)n * 16 + j];
        ax += (float)vv.x; ay += (float)vv.y; az += (float)vv.z; aw += (float)vv.w;
    }
    float* mp = &mol[(long long)cur * 64 + j * 4];
    atomicAdd(mp + 0, ax); atomicAdd(mp + 1, ay);
    atomicAdd(mp + 2, az); atomicAdd(mp + 3, aw);
}

__global__ void head_kernel(const float* __restrict__ mol, const float* __restrict__ W1,
                            const float* __restrict__ b1, const float* __restrict__ W2,
                            const float* __restrict__ b2, float* __restrict__ out) {
    int g = blockIdx.x;
    int j = threadIdx.x;   // 0..127
    float s = b1[j];
#pragma unroll
    for (int k = 0; k < 64; ++k) s = fmaf(mol[g * 64 + k], W1[k * 128 + j], s);
    s = fmaxf(s, 0.0f) * W2[j];
    __shared__ float red[128];
    red[j] = s;
    __syncthreads();
    for (int off = 64; off > 0; off >>= 1) {
        if (j < off) red[j] += red[j + off];
        __syncthreads();
    }
    if (j == 0) out[g] = red[0] + b2[0];
}

extern "C" void kernel_launch(void* const* d_in, const int* in_sizes, int n_in,
                              void* d_out, int out_size, void* d_ws, size_t ws_size,
                              hipStream_t stream) {
    const int*   x          = (const int*)d_in[0];
    const int*   eattr      = (const int*)d_in[1];
    const int*   ei         = (const int*)d_in[2];
    const int*   batch      = (const int*)d_in[3];
    const float* atom_table = (const float*)d_in[4];
    const float* bond_table = (const float*)d_in[5];
    const float* Wi         = (const float*)d_in[6];
    const float* bi         = (const float*)d_in[7];
    const float* Wu         = (const float*)d_in[8];
    const float* bu         = (const float*)d_in[9];
    const float* W1         = (const float*)d_in[10];
    const float* b1         = (const float*)d_in[11];
    const float* W2         = (const float*)d_in[12];
    const float* b2         = (const float*)d_in[13];

    const int N = in_sizes[0];      // 100000
    const int E = in_sizes[1];      // 1600000
    const int M = out_size;         // 2048
    const int AR = in_sizes[4] / 64;                             // 119 atom rows
    const int K = (N + (1 << SLICE_SHIFT) - 1) >> SLICE_SHIFT;   // 98 slices

    char* ws = (char*)d_ws;
    size_t off_b = 0;
    auto alloc = [&](size_t bytes) -> void* {
        void* p = ws + off_b;
        off_b = (off_b + bytes + 255) & ~(size_t)255;
        return p;
    };
    size_t nbytes = (size_t)N * MSG * 2;            // 12.8 MB
    size_t abytes = (size_t)E * 8;                  // 12.8 MB
    _Float16* bufA  = (_Float16*)alloc(nbytes);
    _Float16* bufB  = (_Float16*)alloc(nbytes > abytes ? nbytes : abytes);  // aliased w/ aux
    _Float16* bufC  = (_Float16*)alloc(nbytes);
    unsigned long long* aux = (unsigned long long*)bufB;   // dead before bufB first written
    unsigned* packed = (unsigned*)alloc((size_t)E * 4);
    int*      cnt    = (int*)alloc((size_t)N * 4);
    int*      incl   = (int*)alloc((size_t)N * 4);
    int*      offs   = (int*)alloc((size_t)(N + 1) * 4);
    int*      gcur   = (int*)alloc((size_t)MAXSLICES * 4);
    int*      bsum   = (int*)alloc(1024 * 4);
    _Float16* tAi    = (_Float16*)alloc((size_t)AR * MSG * 2);
    _Float16* tBi    = (_Float16*)alloc((size_t)4 * MSG * 2);
    _Float16* tAu    = (_Float16*)alloc((size_t)AR * MSG * 2);
    _Float16* tBu    = (_Float16*)alloc((size_t)4 * MSG * 2);
    float*    mol    = (float*)alloc((size_t)M * MSG * 4);
    (void)ws_size; (void)n_in;

    // Split tables: tA (119x64, atom term) and tB (4x64, bond term + bias).
    build_tabA_kernel<<<(AR * MSG + 255) / 256, 256, 0, stream>>>(atom_table, Wi, tAi, AR);
    build_tabB_kernel<<<1, 256, 0, stream>>>(bond_table, Wi + 64 * MSG, bi, tBi);
    build_tabA_kernel<<<(AR * MSG + 255) / 256, 256, 0, stream>>>(atom_table, Wu, tAu, AR);
    build_tabB_kernel<<<1, 256, 0, stream>>>(bond_table, Wu + 64 * MSG, bu, tBu);
    node_init_kernel<<<(int)(((long long)N * 16 + 255) / 256), 256, 0, stream>>>(x, tAi, bufC, N);

    // ---- CSR by dst: hist+scan -> offs; radix partition -> aux; place -> packed ----
    const int nb = (N + 1023) / 1024;
    hipMemsetAsync(cnt, 0, (size_t)N * 4, stream);
    hist_kernel<<<(E + 255) / 256, 256, 0, stream>>>(ei, E, cnt);
    scan1_kernel<<<nb, 1024, 0, stream>>>(cnt, incl, bsum, N);
    scan2_kernel<<<1, 64, 0, stream>>>(bsum, nb);
    scan3_kernel<<<nb, 1024, 0, stream>>>(incl, bsum, offs, N);
    binit_kernel<<<1, MAXSLICES, 0, stream>>>(offs, gcur, K, N);
    partition_kernel<<<(E + 1023) / 1024, 256, 0, stream>>>(ei, eattr, E, gcur, aux, K);
    place_kernel<<<K, 1024, 0, stream>>>(aux, offs, packed, N);

    // ---- message passes: single row-gather per edge, tB in registers ----
    const int gblocks = (int)(((long long)N * 16 + 255) / 256);
    const float* Wagg = Wu + 80 * MSG;
    gather_kernel<false><<<gblocks, 256, 0, stream>>>(packed, offs, bufC, tBi, Wagg, tAu, x, bufA, N);
    gather_kernel<false><<<gblocks, 256, 0, stream>>>(packed, offs, bufA, tBu, Wagg, tAu, x, bufB, N);
    gather_kernel<false><<<gblocks, 256, 0, stream>>>(packed, offs, bufB, tBu, Wagg, tAu, x, bufA, N);
    gather_kernel<false><<<gblocks, 256, 0, stream>>>(packed, offs, bufA, tBu, Wagg, tAu, x, bufB, N);
    gather_kernel<true><<<gblocks, 256, 0, stream>>>(packed, offs, bufB, tBu, nullptr, nullptr, nullptr, bufA, N);

    // ---- readout ----
    hipMemsetAsync(mol, 0, (size_t)M * MSG * 4, stream);
    mol_pool_kernel<<<(((N + 31) / 32) * 16 + 255) / 256, 256, 0, stream>>>(bufA, batch, mol, N);
    head_kernel<<<M, 128, 0, stream>>>(mol, W1, b1, W2, b2, (float*)d_out);
}

// Round 9
// 376.296 us; speedup vs baseline: 1.3731x; 1.1460x over previous
//
#include <hip/hip_runtime.h>

#define MSG 64
#define SLICE_SHIFT 10    // 1024 nodes per slice
#define MAXSLICES 128

typedef _Float16 h4 __attribute__((ext_vector_type(4)));
typedef _Float16 h8 __attribute__((ext_vector_type(8)));

__device__ inline h8 relu8(h8 v) {
    h8 z = {};
    return __builtin_elementwise_max(v, z);
}

// tA[a][i] = atom[a] @ W[0:64]   (W ld=64), fp16 out
__global__ void build_tabA_kernel(const float* __restrict__ atom, const float* __restrict__ W,
                                  _Float16* __restrict__ tA, int rows) {
    int t = blockIdx.x * blockDim.x + threadIdx.x;
    if (t >= rows * MSG) return;
    int i = t & 63, a = t >> 6;
    float s = 0.f;
    for (int k = 0; k < 64; ++k) s = fmaf(atom[a * 64 + k], W[k * 64 + i], s);
    tA[t] = (_Float16)s;
}

// tB[b][i] = bias[i] + bond[b] @ W[64:80]   (W16 = W + 64*64), fp16 out. 4 rows.
__global__ void build_tabB_kernel(const float* __restrict__ bond, const float* __restrict__ W16,
                                  const float* __restrict__ bias, _Float16* __restrict__ tB) {
    int t = threadIdx.x;    // 256 = 4 rows * 64
    int i = t & 63, b = t >> 6;
    float s = bias[i];
    for (int k = 0; k < 16; ++k) s = fmaf(bond[b * 16 + k], W16[k * 64 + i], s);
    tB[t] = (_Float16)s;
}

// bufC[v] = tAi[x[v]]  (node-level atom-term table for pass 0)
__global__ void node_init_kernel(const int* __restrict__ x, const _Float16* __restrict__ tA,
                                 _Float16* __restrict__ bufC, int N) {
    int t = blockIdx.x * blockDim.x + threadIdx.x;
    int v = t >> 3, j = t & 7;
    if (v < N) ((h8*)bufC)[(long long)v * 8 + j] = ((const h8*)tA)[x[v] * 8 + j];
}

// Per-slice histogram: LDS-privatized bins, 98 global adds per block.
__global__ void slice_hist_kernel(const int* __restrict__ ei, int E, int* __restrict__ scnt) {
    __shared__ int l[MAXSLICES];
    if (threadIdx.x < MAXSLICES) l[threadIdx.x] = 0;
    __syncthreads();
    int step = gridDim.x * blockDim.x;
    for (int e = blockIdx.x * blockDim.x + threadIdx.x; e < E; e += step)
        atomicAdd(&l[ei[E + e] >> SLICE_SHIFT], 1);
    __syncthreads();
    if (threadIdx.x < MAXSLICES && l[threadIdx.x] > 0)
        atomicAdd(&scnt[threadIdx.x], l[threadIdx.x]);
}

// Exclusive scan of 98 slice counts (serial, trivial) -> sbase; init gcur.
__global__ void scan_slices_kernel(const int* __restrict__ scnt, int* __restrict__ sbase,
                                   int* __restrict__ gcur, int K) {
    if (threadIdx.x == 0 && blockIdx.x == 0) {
        int run = 0;
        for (int s = 0; s < K; ++s) { sbase[s] = run; gcur[s] = run; run += scnt[s]; }
    }
}

// Phase 1: radix-partition edges into dst-slices. Block-local LDS ranking, one
// global atomic per (block,slice), near-contiguous 8B writes.
// record = pw(19b)<<17 | dst(17b), pw = src | eattr<<17.
__global__ __launch_bounds__(256) void partition_kernel(
    const int* __restrict__ ei, const int* __restrict__ eattr,
    int E, int* __restrict__ gcur, unsigned long long* __restrict__ aux, int K)
{
    __shared__ int cnt[MAXSLICES];
    __shared__ int base[MAXSLICES];
    if (threadIdx.x < MAXSLICES) cnt[threadIdx.x] = 0;
    __syncthreads();
    int e0 = blockIdx.x * 1024;
    int sl0 = -1, sl1 = -1, sl2 = -1, sl3 = -1;
    int rk0 = 0, rk1 = 0, rk2 = 0, rk3 = 0;
    unsigned long long p0 = 0, p1 = 0, p2 = 0, p3 = 0;
    {
        int e = e0 + 0 * 256 + threadIdx.x;
        if (e < E) {
            int s = ei[e], d = ei[E + e];
            p0 = ((unsigned long long)((unsigned)s | ((unsigned)eattr[e] << 17)) << 17) | (unsigned)d;
            sl0 = d >> SLICE_SHIFT; rk0 = atomicAdd(&cnt[sl0], 1);
        }
    }
    {
        int e = e0 + 1 * 256 + threadIdx.x;
        if (e < E) {
            int s = ei[e], d = ei[E + e];
            p1 = ((unsigned long long)((unsigned)s | ((unsigned)eattr[e] << 17)) << 17) | (unsigned)d;
            sl1 = d >> SLICE_SHIFT; rk1 = atomicAdd(&cnt[sl1], 1);
        }
    }
    {
        int e = e0 + 2 * 256 + threadIdx.x;
        if (e < E) {
            int s = ei[e], d = ei[E + e];
            p2 = ((unsigned long long)((unsigned)s | ((unsigned)eattr[e] << 17)) << 17) | (unsigned)d;
            sl2 = d >> SLICE_SHIFT; rk2 = atomicAdd(&cnt[sl2], 1);
        }
    }
    {
        int e = e0 + 3 * 256 + threadIdx.x;
        if (e < E) {
            int s = ei[e], d = ei[E + e];
            p3 = ((unsigned long long)((unsigned)s | ((unsigned)eattr[e] << 17)) << 17) | (unsigned)d;
            sl3 = d >> SLICE_SHIFT; rk3 = atomicAdd(&cnt[sl3], 1);
        }
    }
    __syncthreads();
    if (threadIdx.x < K && cnt[threadIdx.x] > 0)
        base[threadIdx.x] = atomicAdd(&gcur[threadIdx.x], cnt[threadIdx.x]);
    __syncthreads();
    if (sl0 >= 0) aux[base[sl0] + rk0] = p0;
    if (sl1 >= 0) aux[base[sl1] + rk1] = p1;
    if (sl2 >= 0) aux[base[sl2] + rk2] = p2;
    if (sl3 >= 0) aux[base[sl3] + rk3] = p3;
}

// Phase 2: one block OWNS one slice. Pass A: count dsts in LDS; block-scan ->
// per-node CSR offsets (written coalesced). Pass B: place records at final
// positions via LDS cursors. All packed-window writes come from one CU.
__global__ __launch_bounds__(1024) void place_kernel(
    const unsigned long long* __restrict__ aux, const int* __restrict__ sbase,
    const int* __restrict__ scnt, int* __restrict__ offs,
    unsigned* __restrict__ packed, int N)
{
    __shared__ int cnt[1 << SLICE_SHIFT];
    __shared__ int wsum[16];
    int s = blockIdx.x;
    int lo = s << SLICE_SHIFT;
    int start = sbase[s];
    int end = start + scnt[s];
    cnt[threadIdx.x] = 0;
    __syncthreads();
    for (int idx = start + threadIdx.x; idx < end; idx += 1024)
        atomicAdd(&cnt[(int)(aux[idx] & 0x1FFFFu) & ((1 << SLICE_SHIFT) - 1)], 1);
    __syncthreads();
    int c = cnt[threadIdx.x];
    // block-wide inclusive scan of 1024 counts
    int lane = threadIdx.x & 63, w = threadIdx.x >> 6;
    int sc = c;
    for (int off = 1; off < 64; off <<= 1) { int t = __shfl_up(sc, off); if (lane >= off) sc += t; }
    if (lane == 63) wsum[w] = sc;
    __syncthreads();
    if (w == 0 && lane < 16) {
        int t = wsum[lane];
        for (int off = 1; off < 16; off <<= 1) { int u = __shfl_up(t, off); if (lane >= off) t += u; }
        wsum[lane] = t;
    }
    __syncthreads();
    if (w > 0) sc += wsum[w - 1];
    int v = lo + threadIdx.x;
    if (v < N) offs[v + 1] = start + sc;
    if (v == 0) offs[0] = 0;
    __syncthreads();
    cnt[threadIdx.x] = start + sc - c;   // node start cursor
    __syncthreads();
    for (int idx = start + threadIdx.x; idx < end; idx += 1024) {
        unsigned long long a = aux[idx];
        int d = (int)(a & 0x1FFFFu);
        unsigned pw = (unsigned)(a >> 17);
        int p = atomicAdd(&cnt[d & ((1 << SLICE_SHIFT) - 1)], 1);
        packed[p] = pw;
    }
}

// 8 lanes per node (h8 = 16B per lane), 32 nodes per 256-thread block.
// acc = sum_{in-edges} relu(nodearr[src] + tB[ea]); tB's 4 rows in registers.
// 64 row-gathers in flight per wave (8 nodes x unroll 8).
// !FINAL epilogue: out[v] = (acc @ Wagg) + tAu[x[v]];  FINAL: out[v] = acc.
template <bool FINAL>
__global__ __launch_bounds__(256) void gather_kernel(
    const unsigned* __restrict__ packed, const int* __restrict__ off,
    const _Float16* __restrict__ nodearr, const _Float16* __restrict__ tB,
    const float* __restrict__ Wagg, const _Float16* __restrict__ tAu,
    const int* __restrict__ x, _Float16* __restrict__ out, int N)
{
    __shared__ float Ws[64 * 64];
    __shared__ float rowbuf[32][68];
    if (!FINAL)
        for (int idx = threadIdx.x; idx < 64 * 64; idx += 256) Ws[idx] = Wagg[idx];
    int t = blockIdx.x * 256 + threadIdx.x;
    int v = t >> 3;                    // node
    int j = threadIdx.x & 7;           // feature octet (8 fp16 = 16B)
    int w = threadIdx.x >> 3;          // group in block (0..31)
    const h8* na8 = (const h8*)nodearr;
    const h8* tB8 = (const h8*)tB;
    h8 tb0 = tB8[0 * 8 + j], tb1 = tB8[1 * 8 + j];
    h8 tb2 = tB8[2 * 8 + j], tb3 = tB8[3 * 8 + j];
    h8 acc = {};
    if (v < N) {
        int e = off[v], end = off[v + 1];
        for (; e + 7 < end; e += 8) {
            unsigned q0 = packed[e],     q1 = packed[e + 1], q2 = packed[e + 2], q3 = packed[e + 3];
            unsigned q4 = packed[e + 4], q5 = packed[e + 5], q6 = packed[e + 6], q7 = packed[e + 7];
            h8 m0 = na8[(q0 & 0x1FFFFu) * 8 + j];
            h8 m1 = na8[(q1 & 0x1FFFFu) * 8 + j];
            h8 m2 = na8[(q2 & 0x1FFFFu) * 8 + j];
            h8 m3 = na8[(q3 & 0x1FFFFu) * 8 + j];
            h8 m4 = na8[(q4 & 0x1FFFFu) * 8 + j];
            h8 m5 = na8[(q5 & 0x1FFFFu) * 8 + j];
            h8 m6 = na8[(q6 & 0x1FFFFu) * 8 + j];
            h8 m7 = na8[(q7 & 0x1FFFFu) * 8 + j];
            unsigned a0 = q0 >> 17, a1 = q1 >> 17, a2 = q2 >> 17, a3 = q3 >> 17;
            unsigned a4 = q4 >> 17, a5 = q5 >> 17, a6 = q6 >> 17, a7 = q7 >> 17;
            h8 s0 = relu8(m0 + ((a0 & 2) ? ((a0 & 1) ? tb3 : tb2) : ((a0 & 1) ? tb1 : tb0)));
            h8 s1 = relu8(m1 + ((a1 & 2) ? ((a1 & 1) ? tb3 : tb2) : ((a1 & 1) ? tb1 : tb0)));
            h8 s2 = relu8(m2 + ((a2 & 2) ? ((a2 & 1) ? tb3 : tb2) : ((a2 & 1) ? tb1 : tb0)));
            h8 s3 = relu8(m3 + ((a3 & 2) ? ((a3 & 1) ? tb3 : tb2) : ((a3 & 1) ? tb1 : tb0)));
            h8 s4 = relu8(m4 + ((a4 & 2) ? ((a4 & 1) ? tb3 : tb2) : ((a4 & 1) ? tb1 : tb0)));
            h8 s5 = relu8(m5 + ((a5 & 2) ? ((a5 & 1) ? tb3 : tb2) : ((a5 & 1) ? tb1 : tb0)));
            h8 s6 = relu8(m6 + ((a6 & 2) ? ((a6 & 1) ? tb3 : tb2) : ((a6 & 1) ? tb1 : tb0)));
            h8 s7 = relu8(m7 + ((a7 & 2) ? ((a7 & 1) ? tb3 : tb2) : ((a7 & 1) ? tb1 : tb0)));
            acc += ((s0 + s1) + (s2 + s3)) + ((s4 + s5) + (s6 + s7));
        }
        for (; e < end; ++e) {
            unsigned q0 = packed[e];
            h8 m0 = na8[(q0 & 0x1FFFFu) * 8 + j];
            unsigned a0 = q0 >> 17;
            acc += relu8(m0 + ((a0 & 2) ? ((a0 & 1) ? tb3 : tb2) : ((a0 & 1) ? tb1 : tb0)));
        }
    }
    if (FINAL) {
        if (v < N) ((h8*)out)[(long long)v * 8 + j] = acc;
        return;
    }
    float* rb = &rowbuf[w][j * 8];
#pragma unroll
    for (int u = 0; u < 8; ++u) rb[u] = (float)acc[u];
    __syncthreads();
    if (v >= N) return;
    const float4* Ws4 = (const float4*)Ws;
    float4 o0 = {0.f, 0.f, 0.f, 0.f}, o1 = {0.f, 0.f, 0.f, 0.f};
#pragma unroll
    for (int k = 0; k < 64; ++k) {
        float r = rowbuf[w][k];
        float4 w0 = Ws4[k * 16 + j * 2];
        float4 w1 = Ws4[k * 16 + j * 2 + 1];
        o0.x = fmaf(r, w0.x, o0.x); o0.y = fmaf(r, w0.y, o0.y);
        o0.z = fmaf(r, w0.z, o0.z); o0.w = fmaf(r, w0.w, o0.w);
        o1.x = fmaf(r, w1.x, o1.x); o1.y = fmaf(r, w1.y, o1.y);
        o1.z = fmaf(r, w1.z, o1.z); o1.w = fmaf(r, w1.w, o1.w);
    }
    h8 ta = ((const h8*)tAu)[x[v] * 8 + j];
    h8 o;
    o[0] = (_Float16)(o0.x + (float)ta[0]); o[1] = (_Float16)(o0.y + (float)ta[1]);
    o[2] = (_Float16)(o0.z + (float)ta[2]); o[3] = (_Float16)(o0.w + (float)ta[3]);
    o[4] = (_Float16)(o1.x + (float)ta[4]); o[5] = (_Float16)(o1.y + (float)ta[5]);
    o[6] = (_Float16)(o1.z + (float)ta[6]); o[7] = (_Float16)(o1.w + (float)ta[7]);
    ((h8*)out)[(long long)v * 8 + j] = o;
}

// batch is sorted: run-length accumulate, flush on mol change. 16 lanes x h4 per 32-node chunk.
__global__ void mol_pool_kernel(const _Float16* __restrict__ ns, const int* __restrict__ batch,
                                float* __restrict__ mol, int N) {
    int g = (blockIdx.x * blockDim.x + threadIdx.x) >> 4;
    int j = threadIdx.x & 15;
    int n0 = g * 32;
    if (n0 >= N) return;
    int n1 = min(n0 + 32, N);
    const h4* ns4 = (const h4*)ns;
    int cur = batch[n0];
    float ax = 0.f, ay = 0.f, az = 0.f, aw = 0.f;
    for (int n = n0; n < n1; ++n) {
        int b = batch[n];
        if (b != cur) {
            float* mp = &mol[(long long)cur * 64 + j * 4];
            atomicAdd(mp + 0, ax); atomicAdd(mp + 1, ay);
            atomicAdd(mp + 2, az); atomicAdd(mp + 3, aw);
            ax = ay = az = aw = 0.f; cur = b;
        }
        h4 vv = ns4[(long long)n * 16 + j];
        ax += (float)vv.x; ay += (float)vv.y; az += (float)vv.z; aw += (float)vv.w;
    }
    float* mp = &mol[(long long)cur * 64 + j * 4];
    atomicAdd(mp + 0, ax); atomicAdd(mp + 1, ay);
    atomicAdd(mp + 2, az); atomicAdd(mp + 3, aw);
}

__global__ void head_kernel(const float* __restrict__ mol, const float* __restrict__ W1,
                            const float* __restrict__ b1, const float* __restrict__ W2,
                            const float* __restrict__ b2, float* __restrict__ out) {
    int g = blockIdx.x;
    int j = threadIdx.x;   // 0..127
    float s = b1[j];
#pragma unroll
    for (int k = 0; k < 64; ++k) s = fmaf(mol[g * 64 + k], W1[k * 128 + j], s);
    s = fmaxf(s, 0.0f) * W2[j];
    __shared__ float red[128];
    red[j] = s;
    __syncthreads();
    for (int off = 64; off > 0; off >>= 1) {
        if (j < off) red[j] += red[j + off];
        __syncthreads();
    }
    if (j == 0) out[g] = red[0] + b2[0];
}

extern "C" void kernel_launch(void* const* d_in, const int* in_sizes, int n_in,
                              void* d_out, int out_size, void* d_ws, size_t ws_size,
                              hipStream_t stream) {
    const int*   x          = (const int*)d_in[0];
    const int*   eattr      = (const int*)d_in[1];
    const int*   ei         = (const int*)d_in[2];
    const int*   batch      = (const int*)d_in[3];
    const float* atom_table = (const float*)d_in[4];
    const float* bond_table = (const float*)d_in[5];
    const float* Wi         = (const float*)d_in[6];
    const float* bi         = (const float*)d_in[7];
    const float* Wu         = (const float*)d_in[8];
    const float* bu         = (const float*)d_in[9];
    const float* W1         = (const float*)d_in[10];
    const float* b1         = (const float*)d_in[11];
    const float* W2         = (const float*)d_in[12];
    const float* b2         = (const float*)d_in[13];

    const int N = in_sizes[0];      // 100000
    const int E = in_sizes[1];      // 1600000
    const int M = out_size;         // 2048
    const int AR = in_sizes[4] / 64;                             // 119 atom rows
    const int K = (N + (1 << SLICE_SHIFT) - 1) >> SLICE_SHIFT;   // 98 slices

    char* ws = (char*)d_ws;
    size_t off_b = 0;
    auto alloc = [&](size_t bytes) -> void* {
        void* p = ws + off_b;
        off_b = (off_b + bytes + 255) & ~(size_t)255;
        return p;
    };
    size_t nbytes = (size_t)N * MSG * 2;            // 12.8 MB
    size_t abytes = (size_t)E * 8;                  // 12.8 MB
    _Float16* bufA  = (_Float16*)alloc(nbytes);
    _Float16* bufB  = (_Float16*)alloc(nbytes > abytes ? nbytes : abytes);  // aliased w/ aux
    _Float16* bufC  = (_Float16*)alloc(nbytes);
    unsigned long long* aux = (unsigned long long*)bufB;   // dead before bufB first written
    unsigned* packed = (unsigned*)alloc((size_t)E * 4);
    int*      offs   = (int*)alloc((size_t)(N + 1) * 4);
    int*      scnt   = (int*)alloc((size_t)MAXSLICES * 4);
    int*      sbase  = (int*)alloc((size_t)MAXSLICES * 4);
    int*      gcur   = (int*)alloc((size_t)MAXSLICES * 4);
    _Float16* tAi    = (_Float16*)alloc((size_t)AR * MSG * 2);
    _Float16* tBi    = (_Float16*)alloc((size_t)4 * MSG * 2);
    _Float16* tAu    = (_Float16*)alloc((size_t)AR * MSG * 2);
    _Float16* tBu    = (_Float16*)alloc((size_t)4 * MSG * 2);
    float*    mol    = (float*)alloc((size_t)M * MSG * 4);
    (void)ws_size; (void)n_in;

    // Split tables: tA (119x64, atom term) and tB (4x64, bond term + bias).
    build_tabA_kernel<<<(AR * MSG + 255) / 256, 256, 0, stream>>>(atom_table, Wi, tAi, AR);
    build_tabB_kernel<<<1, 256, 0, stream>>>(bond_table, Wi + 64 * MSG, bi, tBi);
    build_tabA_kernel<<<(AR * MSG + 255) / 256, 256, 0, stream>>>(atom_table, Wu, tAu, AR);
    build_tabB_kernel<<<1, 256, 0, stream>>>(bond_table, Wu + 64 * MSG, bu, tBu);
    node_init_kernel<<<(int)(((long long)N * 8 + 255) / 256), 256, 0, stream>>>(x, tAi, bufC, N);

    // ---- CSR by dst: slice hist -> 98-scan -> partition -> place (offs + packed) ----
    hipMemsetAsync(scnt, 0, (size_t)MAXSLICES * 4, stream);
    slice_hist_kernel<<<1024, 256, 0, stream>>>(ei, E, scnt);
    scan_slices_kernel<<<1, 64, 0, stream>>>(scnt, sbase, gcur, K);
    partition_kernel<<<(E + 1023) / 1024, 256, 0, stream>>>(ei, eattr, E, gcur, aux, K);
    place_kernel<<<K, 1024, 0, stream>>>(aux, sbase, scnt, offs, packed, N);

    // ---- message passes: single row-gather per edge, tB in registers ----
    const int gblocks = (int)(((long long)N * 8 + 255) / 256);
    const float* Wagg = Wu + 80 * MSG;
    gather_kernel<false><<<gblocks, 256, 0, stream>>>(packed, offs, bufC, tBi, Wagg, tAu, x, bufA, N);
    gather_kernel<false><<<gblocks, 256, 0, stream>>>(packed, offs, bufA, tBu, Wagg, tAu, x, bufB, N);
    gather_kernel<false><<<gblocks, 256, 0, stream>>>(packed, offs, bufB, tBu, Wagg, tAu, x, bufA, N);
    gather_kernel<false><<<gblocks, 256, 0, stream>>>(packed, offs, bufA, tBu, Wagg, tAu, x, bufB, N);
    gather_kernel<true><<<gblocks, 256, 0, stream>>>(packed, offs, bufB, tBu, nullptr, nullptr, nullptr, bufA, N);

    // ---- readout ----
    hipMemsetAsync(mol, 0, (size_t)M * MSG * 4, stream);
    mol_pool_kernel<<<(((N + 31) / 32) * 16 + 255) / 256, 256, 0, stream>>>(bufA, batch, mol, N);
    head_kernel<<<M, 128, 0, stream>>>(mol, W1, b1, W2, b2, (float*)d_out);
}

// Round 10
// 333.137 us; speedup vs baseline: 1.5510x; 1.1296x over previous
//
#include <hip/hip_runtime.h>

#define MSG 64
#define SLICE_SHIFT 10    // 1024 nodes per slice
#define MAXSLICES 128

typedef _Float16 h2 __attribute__((ext_vector_type(2)));
typedef _Float16 h4 __attribute__((ext_vector_type(4)));
typedef _Float16 h8 __attribute__((ext_vector_type(8)));

__device__ inline h8 relu8(h8 v) {
    h8 z = {};
    return __builtin_elementwise_max(v, z);
}

__device__ inline h2 u2h(unsigned u) { union { unsigned u; h2 h; } c; c.u = u; return c.h; }

// tA[a][i] = atom[a] @ W[0:64]   (W ld=64), fp16 out
__global__ void build_tabA_kernel(const float* __restrict__ atom, const float* __restrict__ W,
                                  _Float16* __restrict__ tA, int rows) {
    int t = blockIdx.x * blockDim.x + threadIdx.x;
    if (t >= rows * MSG) return;
    int i = t & 63, a = t >> 6;
    float s = 0.f;
    for (int k = 0; k < 64; ++k) s = fmaf(atom[a * 64 + k], W[k * 64 + i], s);
    tA[t] = (_Float16)s;
}

// tB[b][i] = bias[i] + bond[b] @ W[64:80]   (W16 = W + 64*64), fp16 out. 4 rows.
__global__ void build_tabB_kernel(const float* __restrict__ bond, const float* __restrict__ W16,
                                  const float* __restrict__ bias, _Float16* __restrict__ tB) {
    int t = threadIdx.x;    // 256 = 4 rows * 64
    int i = t & 63, b = t >> 6;
    float s = bias[i];
    for (int k = 0; k < 16; ++k) s = fmaf(bond[b * 16 + k], W16[k * 64 + i], s);
    tB[t] = (_Float16)s;
}

// wst[k2][c] = pack_h2(W[2k2][c], W[2k2+1][c])  — fp16-interleaved Wagg for v_dot2.
__global__ void build_tabW_kernel(const float* __restrict__ W, unsigned* __restrict__ wst) {
    int t = blockIdx.x * 256 + threadIdx.x;   // 2048 = 32 * 64
    if (t >= 2048) return;
    int k2 = t >> 6, c = t & 63;
    h2 h; h[0] = (_Float16)W[(2 * k2) * 64 + c]; h[1] = (_Float16)W[(2 * k2 + 1) * 64 + c];
    union { h2 h; unsigned u; } cv; cv.h = h;
    wst[k2 * 64 + c] = cv.u;
}

// bufC[v] = tAi[x[v]]  (node-level atom-term table for pass 0)
__global__ void node_init_kernel(const int* __restrict__ x, const _Float16* __restrict__ tA,
                                 _Float16* __restrict__ bufC, int N) {
    int t = blockIdx.x * blockDim.x + threadIdx.x;
    int v = t >> 3, j = t & 7;
    if (v < N) ((h8*)bufC)[(long long)v * 8 + j] = ((const h8*)tA)[x[v] * 8 + j];
}

// Per-slice histogram: LDS-privatized bins, 98 global adds per block.
__global__ void slice_hist_kernel(const int* __restrict__ ei, int E, int* __restrict__ scnt) {
    __shared__ int l[MAXSLICES];
    if (threadIdx.x < MAXSLICES) l[threadIdx.x] = 0;
    __syncthreads();
    int step = gridDim.x * blockDim.x;
    for (int e = blockIdx.x * blockDim.x + threadIdx.x; e < E; e += step)
        atomicAdd(&l[ei[E + e] >> SLICE_SHIFT], 1);
    __syncthreads();
    if (threadIdx.x < MAXSLICES && l[threadIdx.x] > 0)
        atomicAdd(&scnt[threadIdx.x], l[threadIdx.x]);
}

// Exclusive scan of 98 slice counts (serial, trivial) -> sbase; init gcur.
__global__ void scan_slices_kernel(const int* __restrict__ scnt, int* __restrict__ sbase,
                                   int* __restrict__ gcur, int K) {
    if (threadIdx.x == 0 && blockIdx.x == 0) {
        int run = 0;
        for (int s = 0; s < K; ++s) { sbase[s] = run; gcur[s] = run; run += scnt[s]; }
    }
}

// Phase 1: radix-partition edges into dst-slices. Block-local LDS ranking, one
// global atomic per (block,slice), near-contiguous 8B writes.
// record = pw(19b)<<17 | dst(17b), pw = src | eattr<<17.
__global__ __launch_bounds__(256) void partition_kernel(
    const int* __restrict__ ei, const int* __restrict__ eattr,
    int E, int* __restrict__ gcur, unsigned long long* __restrict__ aux, int K)
{
    __shared__ int cnt[MAXSLICES];
    __shared__ int base[MAXSLICES];
    if (threadIdx.x < MAXSLICES) cnt[threadIdx.x] = 0;
    __syncthreads();
    int e0 = blockIdx.x * 1024;
    int sl0 = -1, sl1 = -1, sl2 = -1, sl3 = -1;
    int rk0 = 0, rk1 = 0, rk2 = 0, rk3 = 0;
    unsigned long long p0 = 0, p1 = 0, p2 = 0, p3 = 0;
    {
        int e = e0 + 0 * 256 + threadIdx.x;
        if (e < E) {
            int s = ei[e], d = ei[E + e];
            p0 = ((unsigned long long)((unsigned)s | ((unsigned)eattr[e] << 17)) << 17) | (unsigned)d;
            sl0 = d >> SLICE_SHIFT; rk0 = atomicAdd(&cnt[sl0], 1);
        }
    }
    {
        int e = e0 + 1 * 256 + threadIdx.x;
        if (e < E) {
            int s = ei[e], d = ei[E + e];
            p1 = ((unsigned long long)((unsigned)s | ((unsigned)eattr[e] << 17)) << 17) | (unsigned)d;
            sl1 = d >> SLICE_SHIFT; rk1 = atomicAdd(&cnt[sl1], 1);
        }
    }
    {
        int e = e0 + 2 * 256 + threadIdx.x;
        if (e < E) {
            int s = ei[e], d = ei[E + e];
            p2 = ((unsigned long long)((unsigned)s | ((unsigned)eattr[e] << 17)) << 17) | (unsigned)d;
            sl2 = d >> SLICE_SHIFT; rk2 = atomicAdd(&cnt[sl2], 1);
        }
    }
    {
        int e = e0 + 3 * 256 + threadIdx.x;
        if (e < E) {
            int s = ei[e], d = ei[E + e];
            p3 = ((unsigned long long)((unsigned)s | ((unsigned)eattr[e] << 17)) << 17) | (unsigned)d;
            sl3 = d >> SLICE_SHIFT; rk3 = atomicAdd(&cnt[sl3], 1);
        }
    }
    __syncthreads();
    if (threadIdx.x < K && cnt[threadIdx.x] > 0)
        base[threadIdx.x] = atomicAdd(&gcur[threadIdx.x], cnt[threadIdx.x]);
    __syncthreads();
    if (sl0 >= 0) aux[base[sl0] + rk0] = p0;
    if (sl1 >= 0) aux[base[sl1] + rk1] = p1;
    if (sl2 >= 0) aux[base[sl2] + rk2] = p2;
    if (sl3 >= 0) aux[base[sl3] + rk3] = p3;
}

// Phase 2: one block OWNS one slice. Pass A: count dsts in LDS; block-scan ->
// per-node CSR offsets (written coalesced). Pass B: place records at final
// positions via LDS cursors. All packed-window writes come from one CU.
__global__ __launch_bounds__(1024) void place_kernel(
    const unsigned long long* __restrict__ aux, const int* __restrict__ sbase,
    const int* __restrict__ scnt, int* __restrict__ offs,
    unsigned* __restrict__ packed, int N)
{
    __shared__ int cnt[1 << SLICE_SHIFT];
    __shared__ int wsum[16];
    int s = blockIdx.x;
    int lo = s << SLICE_SHIFT;
    int start = sbase[s];
    int end = start + scnt[s];
    cnt[threadIdx.x] = 0;
    __syncthreads();
    for (int idx = start + threadIdx.x; idx < end; idx += 1024)
        atomicAdd(&cnt[(int)(aux[idx] & 0x1FFFFu) & ((1 << SLICE_SHIFT) - 1)], 1);
    __syncthreads();
    int c = cnt[threadIdx.x];
    // block-wide inclusive scan of 1024 counts
    int lane = threadIdx.x & 63, w = threadIdx.x >> 6;
    int sc = c;
    for (int off = 1; off < 64; off <<= 1) { int t = __shfl_up(sc, off); if (lane >= off) sc += t; }
    if (lane == 63) wsum[w] = sc;
    __syncthreads();
    if (w == 0 && lane < 16) {
        int t = wsum[lane];
        for (int off = 1; off < 16; off <<= 1) { int u = __shfl_up(t, off); if (lane >= off) t += u; }
        wsum[lane] = t;
    }
    __syncthreads();
    if (w > 0) sc += wsum[w - 1];
    int v = lo + threadIdx.x;
    if (v < N) offs[v + 1] = start + sc;
    if (v == 0) offs[0] = 0;
    __syncthreads();
    cnt[threadIdx.x] = start + sc - c;   // node start cursor
    __syncthreads();
    for (int idx = start + threadIdx.x; idx < end; idx += 1024) {
        unsigned long long a = aux[idx];
        int d = (int)(a & 0x1FFFFu);
        unsigned pw = (unsigned)(a >> 17);
        int p = atomicAdd(&cnt[d & ((1 << SLICE_SHIFT) - 1)], 1);
        packed[p] = pw;
    }
}

// 8 lanes per node (h8 = 16B per lane), 32 nodes per 256-thread block.
// acc = sum_{in-edges} relu(nodearr[src] + tB[ea]); tB in 512B LDS (ds_read_b128),
// NOT register-selects. Epilogue GEMM via v_dot2_f32_f16 on fp16-interleaved wst.
// !FINAL: out[v] = (acc @ Wagg) + tAu[x[v]];  FINAL: out[v] = acc.
template <bool FINAL>
__global__ __launch_bounds__(256) void gather_kernel(
    const unsigned* __restrict__ packed, const int* __restrict__ off,
    const _Float16* __restrict__ nodearr, const _Float16* __restrict__ tB,
    const unsigned* __restrict__ wst_g, const _Float16* __restrict__ tAu,
    const int* __restrict__ x, _Float16* __restrict__ out, int N)
{
    __shared__ _Float16 tbs[4 * 64];       // 512B bond table
    __shared__ unsigned wst[32 * 64];      // 8KB fp16-pair Wagg (unused if FINAL)
    __shared__ _Float16 rowb[32][72];      // 4.6KB fp16 row staging (pad 72: conflict-free)
    tbs[threadIdx.x] = tB[threadIdx.x];    // 256 = 4*64
    if (!FINAL)
        for (int idx = threadIdx.x; idx < 2048; idx += 256) wst[idx] = wst_g[idx];
    __syncthreads();
    int t = blockIdx.x * 256 + threadIdx.x;
    int v = t >> 3;                    // node
    int j = threadIdx.x & 7;           // feature octet (8 fp16 = 16B)
    int w = threadIdx.x >> 3;          // group in block (0..31)
    const h8* na8 = (const h8*)nodearr;
    const _Float16* tbsj = tbs + j * 8;
    h8 acc = {};
    if (v < N) {
        int e = off[v], end = off[v + 1];
        for (; e + 7 < end; e += 8) {
            unsigned q0 = packed[e],     q1 = packed[e + 1], q2 = packed[e + 2], q3 = packed[e + 3];
            unsigned q4 = packed[e + 4], q5 = packed[e + 5], q6 = packed[e + 6], q7 = packed[e + 7];
            h8 m0 = na8[(q0 & 0x1FFFFu) * 8 + j];
            h8 m1 = na8[(q1 & 0x1FFFFu) * 8 + j];
            h8 m2 = na8[(q2 & 0x1FFFFu) * 8 + j];
            h8 m3 = na8[(q3 & 0x1FFFFu) * 8 + j];
            h8 m4 = na8[(q4 & 0x1FFFFu) * 8 + j];
            h8 m5 = na8[(q5 & 0x1FFFFu) * 8 + j];
            h8 m6 = na8[(q6 & 0x1FFFFu) * 8 + j];
            h8 m7 = na8[(q7 & 0x1FFFFu) * 8 + j];
            h8 t0 = *(const h8*)&tbsj[(q0 >> 17) * 64];
            h8 t1 = *(const h8*)&tbsj[(q1 >> 17) * 64];
            h8 t2 = *(const h8*)&tbsj[(q2 >> 17) * 64];
            h8 t3 = *(const h8*)&tbsj[(q3 >> 17) * 64];
            h8 t4 = *(const h8*)&tbsj[(q4 >> 17) * 64];
            h8 t5 = *(const h8*)&tbsj[(q5 >> 17) * 64];
            h8 t6 = *(const h8*)&tbsj[(q6 >> 17) * 64];
            h8 t7 = *(const h8*)&tbsj[(q7 >> 17) * 64];
            h8 s0 = relu8(m0 + t0), s1 = relu8(m1 + t1);
            h8 s2 = relu8(m2 + t2), s3 = relu8(m3 + t3);
            h8 s4 = relu8(m4 + t4), s5 = relu8(m5 + t5);
            h8 s6 = relu8(m6 + t6), s7 = relu8(m7 + t7);
            acc += ((s0 + s1) + (s2 + s3)) + ((s4 + s5) + (s6 + s7));
        }
        for (; e < end; ++e) {
            unsigned q0 = packed[e];
            h8 m0 = na8[(q0 & 0x1FFFFu) * 8 + j];
            h8 t0 = *(const h8*)&tbsj[(q0 >> 17) * 64];
            acc += relu8(m0 + t0);
        }
    }
    if (FINAL) {
        if (v < N) ((h8*)out)[(long long)v * 8 + j] = acc;
        return;
    }
    *(h8*)&rowb[w][j * 8] = acc;
    __syncthreads();
    if (v >= N) return;
    const h2* rp = (const h2*)&rowb[w][0];
    const unsigned* wj = wst + j * 8;
    float o0 = 0.f, o1 = 0.f, o2 = 0.f, o3 = 0.f, o4 = 0.f, o5 = 0.f, o6 = 0.f, o7 = 0.f;
#pragma unroll
    for (int k2 = 0; k2 < 32; ++k2) {
        h2 r = rp[k2];
        uint4 wa = *(const uint4*)&wj[k2 * 64];
        uint4 wb = *(const uint4*)&wj[k2 * 64 + 4];
        o0 = __builtin_amdgcn_fdot2(r, u2h(wa.x), o0, false);
        o1 = __builtin_amdgcn_fdot2(r, u2h(wa.y), o1, false);
        o2 = __builtin_amdgcn_fdot2(r, u2h(wa.z), o2, false);
        o3 = __builtin_amdgcn_fdot2(r, u2h(wa.w), o3, false);
        o4 = __builtin_amdgcn_fdot2(r, u2h(wb.x), o4, false);
        o5 = __builtin_amdgcn_fdot2(r, u2h(wb.y), o5, false);
        o6 = __builtin_amdgcn_fdot2(r, u2h(wb.z), o6, false);
        o7 = __builtin_amdgcn_fdot2(r, u2h(wb.w), o7, false);
    }
    h8 ta = ((const h8*)tAu)[x[v] * 8 + j];
    h8 o;
    o[0] = (_Float16)(o0 + (float)ta[0]); o[1] = (_Float16)(o1 + (float)ta[1]);
    o[2] = (_Float16)(o2 + (float)ta[2]); o[3] = (_Float16)(o3 + (float)ta[3]);
    o[4] = (_Float16)(o4 + (float)ta[4]); o[5] = (_Float16)(o5 + (float)ta[5]);
    o[6] = (_Float16)(o6 + (float)ta[6]); o[7] = (_Float16)(o7 + (float)ta[7]);
    ((h8*)out)[(long long)v * 8 + j] = o;
}

// batch is sorted: run-length accumulate, flush on mol change. 16 lanes x h4 per 32-node chunk.
__global__ void mol_pool_kernel(const _Float16* __restrict__ ns, const int* __restrict__ batch,
                                float* __restrict__ mol, int N) {
    int g = (blockIdx.x * blockDim.x + threadIdx.x) >> 4;
    int j = threadIdx.x & 15;
    int n0 = g * 32;
    if (n0 >= N) return;
    int n1 = min(n0 + 32, N);
    const h4* ns4 = (const h4*)ns;
    int cur = batch[n0];
    float ax = 0.f, ay = 0.f, az = 0.f, aw = 0.f;
    for (int n = n0; n < n1; ++n) {
        int b = batch[n];
        if (b != cur) {
            float* mp = &mol[(long long)cur * 64 + j * 4];
            atomicAdd(mp + 0, ax); atomicAdd(mp + 1, ay);
            atomicAdd(mp + 2, az); atomicAdd(mp + 3, aw);
            ax = ay = az = aw = 0.f; cur = b;
        }
        h4 vv = ns4[(long long)n * 16 + j];
        ax += (float)vv.x; ay += (float)vv.y; az += (float)vv.z; aw += (float)vv.w;
    }
    float* mp = &mol[(long long)cur * 64 + j * 4];
    atomicAdd(mp + 0, ax); atomicAdd(mp + 1, ay);
    atomicAdd(mp + 2, az); atomicAdd(mp + 3, aw);
}

__global__ void head_kernel(const float* __restrict__ mol, const float* __restrict__ W1,
                            const float* __restrict__ b1, const float* __restrict__ W2,
                            const float* __restrict__ b2, float* __restrict__ out) {
    int g = blockIdx.x;
    int j = threadIdx.x;   // 0..127
    float s = b1[j];
#pragma unroll
    for (int k = 0; k < 64; ++k) s = fmaf(mol[g * 64 + k], W1[k * 128 + j], s);
    s = fmaxf(s, 0.0f) * W2[j];
    __shared__ float red[128];
    red[j] = s;
    __syncthreads();
    for (int off = 64; off > 0; off >>= 1) {
        if (j < off) red[j] += red[j + off];
        __syncthreads();
    }
    if (j == 0) out[g] = red[0] + b2[0];
}

extern "C" void kernel_launch(void* const* d_in, const int* in_sizes, int n_in,
                              void* d_out, int out_size, void* d_ws, size_t ws_size,
                              hipStream_t stream) {
    const int*   x          = (const int*)d_in[0];
    const int*   eattr      = (const int*)d_in[1];
    const int*   ei         = (const int*)d_in[2];
    const int*   batch      = (const int*)d_in[3];
    const float* atom_table = (const float*)d_in[4];
    const float* bond_table = (const float*)d_in[5];
    const float* Wi         = (const float*)d_in[6];
    const float* bi         = (const float*)d_in[7];
    const float* Wu         = (const float*)d_in[8];
    const float* bu         = (const float*)d_in[9];
    const float* W1         = (const float*)d_in[10];
    const float* b1         = (const float*)d_in[11];
    const float* W2         = (const float*)d_in[12];
    const float* b2         = (const float*)d_in[13];

    const int N = in_sizes[0];      // 100000
    const int E = in_sizes[1];      // 1600000
    const int M = out_size;         // 2048
    const int AR = in_sizes[4] / 64;                             // 119 atom rows
    const int K = (N + (1 << SLICE_SHIFT) - 1) >> SLICE_SHIFT;   // 98 slices

    char* ws = (char*)d_ws;
    size_t off_b = 0;
    auto alloc = [&](size_t bytes) -> void* {
        void* p = ws + off_b;
        off_b = (off_b + bytes + 255) & ~(size_t)255;
        return p;
    };
    size_t nbytes = (size_t)N * MSG * 2;            // 12.8 MB
    size_t abytes = (size_t)E * 8;                  // 12.8 MB
    _Float16* bufA  = (_Float16*)alloc(nbytes);
    _Float16* bufB  = (_Float16*)alloc(nbytes > abytes ? nbytes : abytes);  // aliased w/ aux
    _Float16* bufC  = (_Float16*)alloc(nbytes);
    unsigned long long* aux = (unsigned long long*)bufB;   // dead before bufB first written
    unsigned* packed = (unsigned*)alloc((size_t)E * 4);
    int*      offs   = (int*)alloc((size_t)(N + 1) * 4);
    int*      scnt   = (int*)alloc((size_t)MAXSLICES * 4);
    int*      sbase  = (int*)alloc((size_t)MAXSLICES * 4);
    int*      gcur   = (int*)alloc((size_t)MAXSLICES * 4);
    _Float16* tAi    = (_Float16*)alloc((size_t)AR * MSG * 2);
    _Float16* tBi    = (_Float16*)alloc((size_t)4 * MSG * 2);
    _Float16* tAu    = (_Float16*)alloc((size_t)AR * MSG * 2);
    _Float16* tBu    = (_Float16*)alloc((size_t)4 * MSG * 2);
    unsigned* wstb   = (unsigned*)alloc((size_t)32 * 64 * 4);
    float*    mol    = (float*)alloc((size_t)M * MSG * 4);
    (void)ws_size; (void)n_in;

    // Tables: tA (119x64 atom term), tB (4x64 bond term + bias), wst (fp16-pair Wagg).
    const float* Wagg = Wu + 80 * MSG;
    build_tabA_kernel<<<(AR * MSG + 255) / 256, 256, 0, stream>>>(atom_table, Wi, tAi, AR);
    build_tabB_kernel<<<1, 256, 0, stream>>>(bond_table, Wi + 64 * MSG, bi, tBi);
    build_tabA_kernel<<<(AR * MSG + 255) / 256, 256, 0, stream>>>(atom_table, Wu, tAu, AR);
    build_tabB_kernel<<<1, 256, 0, stream>>>(bond_table, Wu + 64 * MSG, bu, tBu);
    build_tabW_kernel<<<8, 256, 0, stream>>>(Wagg, wstb);
    node_init_kernel<<<(int)(((long long)N * 8 + 255) / 256), 256, 0, stream>>>(x, tAi, bufC, N);

    // ---- CSR by dst: slice hist -> 98-scan -> partition -> place (offs + packed) ----
    hipMemsetAsync(scnt, 0, (size_t)MAXSLICES * 4, stream);
    slice_hist_kernel<<<1024, 256, 0, stream>>>(ei, E, scnt);
    scan_slices_kernel<<<1, 64, 0, stream>>>(scnt, sbase, gcur, K);
    partition_kernel<<<(E + 1023) / 1024, 256, 0, stream>>>(ei, eattr, E, gcur, aux, K);
    place_kernel<<<K, 1024, 0, stream>>>(aux, sbase, scnt, offs, packed, N);

    // ---- message passes: single row-gather per edge, tB in LDS, dot2 epilogue ----
    const int gblocks = (int)(((long long)N * 8 + 255) / 256);
    gather_kernel<false><<<gblocks, 256, 0, stream>>>(packed, offs, bufC, tBi, wstb, tAu, x, bufA, N);
    gather_kernel<false><<<gblocks, 256, 0, stream>>>(packed, offs, bufA, tBu, wstb, tAu, x, bufB, N);
    gather_kernel<false><<<gblocks, 256, 0, stream>>>(packed, offs, bufB, tBu, wstb, tAu, x, bufA, N);
    gather_kernel<false><<<gblocks, 256, 0, stream>>>(packed, offs, bufA, tBu, wstb, tAu, x, bufB, N);
    gather_kernel<true><<<gblocks, 256, 0, stream>>>(packed, offs, bufB, tBu, nullptr, nullptr, nullptr, bufA, N);

    // ---- readout ----
    hipMemsetAsync(mol, 0, (size_t)M * MSG * 4, stream);
    mol_pool_kernel<<<(((N + 31) / 32) * 16 + 255) / 256, 256, 0, stream>>>(bufA, batch, mol, N);
    head_kernel<<<M, 128, 0, stream>>>(mol, W1, b1, W2, b2, (float*)d_out);
}

// Round 11
// 313.595 us; speedup vs baseline: 1.6477x; 1.0623x over previous
//
#include <hip/hip_runtime.h>

#define MSG 64
#define SLICE_SHIFT 10     // 1024 nodes per slice
#define MAXSLICES 128
#define CAP_E 20480        // edges per slice region (mean 16384, +32 sigma)
#define CAP_B 16384        // nodes per degree bucket (max bucket ~10.3K)
#define NBIN 64

typedef _Float16 h2 __attribute__((ext_vector_type(2)));
typedef _Float16 h4 __attribute__((ext_vector_type(4)));
typedef _Float16 h8 __attribute__((ext_vector_type(8)));

__device__ inline h8 relu8(h8 v) {
    h8 z = {};
    return __builtin_elementwise_max(v, z);
}

__device__ inline h2 u2h(unsigned u) { union { unsigned u; h2 h; } c; c.u = u; return c.h; }

// tA[a][i] = atom[a] @ W[0:64]   (W ld=64), fp16 out
__global__ void build_tabA_kernel(const float* __restrict__ atom, const float* __restrict__ W,
                                  _Float16* __restrict__ tA, int rows) {
    int t = blockIdx.x * blockDim.x + threadIdx.x;
    if (t >= rows * MSG) return;
    int i = t & 63, a = t >> 6;
    float s = 0.f;
    for (int k = 0; k < 64; ++k) s = fmaf(atom[a * 64 + k], W[k * 64 + i], s);
    tA[t] = (_Float16)s;
}

// tB[b][i] = bias[i] + bond[b] @ W[64:80]   (W16 = W + 64*64), fp16 out. 4 rows.
__global__ void build_tabB_kernel(const float* __restrict__ bond, const float* __restrict__ W16,
                                  const float* __restrict__ bias, _Float16* __restrict__ tB) {
    int t = threadIdx.x;    // 256 = 4 rows * 64
    int i = t & 63, b = t >> 6;
    float s = bias[i];
    for (int k = 0; k < 16; ++k) s = fmaf(bond[b * 16 + k], W16[k * 64 + i], s);
    tB[t] = (_Float16)s;
}

// wst[k2][c] = pack_h2(W[2k2][c], W[2k2+1][c])  — fp16-interleaved Wagg for v_dot2.
__global__ void build_tabW_kernel(const float* __restrict__ W, unsigned* __restrict__ wst) {
    int t = blockIdx.x * 256 + threadIdx.x;   // 2048 = 32 * 64
    if (t >= 2048) return;
    int k2 = t >> 6, c = t & 63;
    h2 h; h[0] = (_Float16)W[(2 * k2) * 64 + c]; h[1] = (_Float16)W[(2 * k2 + 1) * 64 + c];
    union { h2 h; unsigned u; } cv; cv.h = h;
    wst[k2 * 64 + c] = cv.u;
}

// bufC[v] = tAi[x[v]]  (node-level atom-term table for pass 0)
__global__ void node_init_kernel(const int* __restrict__ x, const _Float16* __restrict__ tA,
                                 _Float16* __restrict__ bufC, int N) {
    int t = blockIdx.x * blockDim.x + threadIdx.x;
    int v = t >> 3, j = t & 7;
    if (v < N) ((h8*)bufC)[(long long)v * 8 + j] = ((const h8*)tA)[x[v] * 8 + j];
}

// gcur[s] = s*CAP_E (fixed-capacity slice regions; no global scan needed)
__global__ void ginit_kernel(int* __restrict__ gcur, int K) {
    int s = blockIdx.x * blockDim.x + threadIdx.x;
    if (s < K) gcur[s] = s * CAP_E;
}

// Phase 1: radix-partition edges into fixed-cap dst-slice regions. Block-local
// LDS ranking, one global atomic per (block,slice), near-contiguous 8B writes.
// record = pw(19b)<<17 | dst(17b), pw = src | eattr<<17.
__global__ __launch_bounds__(256) void partition_kernel(
    const int* __restrict__ ei, const int* __restrict__ eattr,
    int E, int* __restrict__ gcur, unsigned long long* __restrict__ aux, int K)
{
    __shared__ int cnt[MAXSLICES];
    __shared__ int base[MAXSLICES];
    if (threadIdx.x < MAXSLICES) cnt[threadIdx.x] = 0;
    __syncthreads();
    int e0 = blockIdx.x * 1024;
    int sl0 = -1, sl1 = -1, sl2 = -1, sl3 = -1;
    int rk0 = 0, rk1 = 0, rk2 = 0, rk3 = 0;
    unsigned long long p0 = 0, p1 = 0, p2 = 0, p3 = 0;
    {
        int e = e0 + 0 * 256 + threadIdx.x;
        if (e < E) {
            int s = ei[e], d = ei[E + e];
            p0 = ((unsigned long long)((unsigned)s | ((unsigned)eattr[e] << 17)) << 17) | (unsigned)d;
            sl0 = d >> SLICE_SHIFT; rk0 = atomicAdd(&cnt[sl0], 1);
        }
    }
    {
        int e = e0 + 1 * 256 + threadIdx.x;
        if (e < E) {
            int s = ei[e], d = ei[E + e];
            p1 = ((unsigned long long)((unsigned)s | ((unsigned)eattr[e] << 17)) << 17) | (unsigned)d;
            sl1 = d >> SLICE_SHIFT; rk1 = atomicAdd(&cnt[sl1], 1);
        }
    }
    {
        int e = e0 + 2 * 256 + threadIdx.x;
        if (e < E) {
            int s = ei[e], d = ei[E + e];
            p2 = ((unsigned long long)((unsigned)s | ((unsigned)eattr[e] << 17)) << 17) | (unsigned)d;
            sl2 = d >> SLICE_SHIFT; rk2 = atomicAdd(&cnt[sl2], 1);
        }
    }
    {
        int e = e0 + 3 * 256 + threadIdx.x;
        if (e < E) {
            int s = ei[e], d = ei[E + e];
            p3 = ((unsigned long long)((unsigned)s | ((unsigned)eattr[e] << 17)) << 17) | (unsigned)d;
            sl3 = d >> SLICE_SHIFT; rk3 = atomicAdd(&cnt[sl3], 1);
        }
    }
    __syncthreads();
    if (threadIdx.x < K && cnt[threadIdx.x] > 0)
        base[threadIdx.x] = atomicAdd(&gcur[threadIdx.x], cnt[threadIdx.x]);
    __syncthreads();
    if (sl0 >= 0) aux[base[sl0] + rk0] = p0;
    if (sl1 >= 0) aux[base[sl1] + rk1] = p1;
    if (sl2 >= 0) aux[base[sl2] + rk2] = p2;
    if (sl3 >= 0) aux[base[sl3] + rk3] = p3;
}

// Phase 2: one block OWNS one slice. Pass A: count dsts in LDS; block-scan ->
// per-node start/deg (coalesced). Pass B: place records via LDS cursors.
// All packed-window writes come from one CU.
__global__ __launch_bounds__(1024) void place_kernel(
    const unsigned long long* __restrict__ aux, const int* __restrict__ gcur,
    int* __restrict__ nstart, int* __restrict__ ndeg,
    unsigned* __restrict__ packed, int N)
{
    __shared__ int cnt[1 << SLICE_SHIFT];
    __shared__ int wsum[16];
    int s = blockIdx.x;
    int lo = s << SLICE_SHIFT;
    int start = s * CAP_E;
    int end = gcur[s];
    cnt[threadIdx.x] = 0;
    __syncthreads();
    for (int idx = start + threadIdx.x; idx < end; idx += 1024)
        atomicAdd(&cnt[(int)(aux[idx] & 0x1FFFFu) & ((1 << SLICE_SHIFT) - 1)], 1);
    __syncthreads();
    int c = cnt[threadIdx.x];
    int lane = threadIdx.x & 63, w = threadIdx.x >> 6;
    int sc = c;
    for (int off = 1; off < 64; off <<= 1) { int t = __shfl_up(sc, off); if (lane >= off) sc += t; }
    if (lane == 63) wsum[w] = sc;
    __syncthreads();
    if (w == 0 && lane < 16) {
        int t = wsum[lane];
        for (int off = 1; off < 16; off <<= 1) { int u = __shfl_up(t, off); if (lane >= off) t += u; }
        wsum[lane] = t;
    }
    __syncthreads();
    if (w > 0) sc += wsum[w - 1];
    int v = lo + threadIdx.x;
    int st = start + sc - c;
    if (v < N) { nstart[v] = st; ndeg[v] = c; }
    __syncthreads();
    cnt[threadIdx.x] = st;
    __syncthreads();
    for (int idx = start + threadIdx.x; idx < end; idx += 1024) {
        unsigned long long a = aux[idx];
        int d = (int)(a & 0x1FFFFu);
        unsigned pw = (unsigned)(a >> 17);
        int p = atomicAdd(&cnt[d & ((1 << SLICE_SHIFT) - 1)], 1);
        packed[p] = pw;
    }
}

// Degree-bucket partition of nodes (same LDS-rank pattern): bucket[bin] gets
// node ids; order within bucket arbitrary. bin = min(deg, 63).
__global__ __launch_bounds__(256) void dbin_kernel(const int* __restrict__ ndeg, int N,
                                                   int* __restrict__ bcnt, int* __restrict__ bucket) {
    __shared__ int cnt[NBIN];
    __shared__ int base[NBIN];
    if (threadIdx.x < NBIN) cnt[threadIdx.x] = 0;
    __syncthreads();
    int v = blockIdx.x * 256 + threadIdx.x;
    int b = -1, rk = 0;
    if (v < N) { b = min(ndeg[v], NBIN - 1); rk = atomicAdd(&cnt[b], 1); }
    __syncthreads();
    if (threadIdx.x < NBIN && cnt[threadIdx.x] > 0)
        base[threadIdx.x] = atomicAdd(&bcnt[threadIdx.x], cnt[threadIdx.x]);
    __syncthreads();
    if (b >= 0) bucket[b * CAP_B + base[b] + rk] = v;
}

__global__ void bscan_kernel(const int* __restrict__ bcnt, int* __restrict__ bbase) {
    if (threadIdx.x == 0 && blockIdx.x == 0) {
        int run = 0;
        for (int b = 0; b < NBIN; ++b) { bbase[b] = run; run += bcnt[b]; }
    }
}

// Compact buckets -> srt[v'] = {edge_start, v | deg<<17}  (degree-sorted node order)
__global__ void compact_kernel(const int* __restrict__ bucket, const int* __restrict__ bcnt,
                               const int* __restrict__ bbase, const int* __restrict__ nstart,
                               const int* __restrict__ ndeg, int2* __restrict__ srt) {
    int b = blockIdx.x;
    int n = bcnt[b], base = bbase[b];
    for (int i = threadIdx.x; i < n; i += 256) {
        int v = bucket[b * CAP_B + i];
        srt[base + i] = make_int2(nstart[v], v | (ndeg[v] << 17));
    }
}

// 8 lanes per node (h8 = 16B per lane), 32 nodes per 256-thread block, nodes in
// DEGREE-SORTED order via srt (wave/block divergence ~0).
// acc = sum_{in-edges} relu(nodearr[src] + tB[ea]); tB in 512B LDS.
// Epilogue GEMM via v_dot2_f32_f16. !FINAL: out[v]=(acc@Wagg)+tAu[x[v]]; FINAL: out[v]=acc.
template <bool FINAL>
__global__ __launch_bounds__(256) void gather_kernel(
    const unsigned* __restrict__ packed, const int2* __restrict__ srt,
    const _Float16* __restrict__ nodearr, const _Float16* __restrict__ tB,
    const unsigned* __restrict__ wst_g, const _Float16* __restrict__ tAu,
    const int* __restrict__ x, _Float16* __restrict__ out, int N)
{
    __shared__ _Float16 tbs[4 * 64];
    __shared__ unsigned wst[32 * 64];
    __shared__ _Float16 rowb[32][72];
    tbs[threadIdx.x] = tB[threadIdx.x];
    if (!FINAL)
        for (int idx = threadIdx.x; idx < 2048; idx += 256) wst[idx] = wst_g[idx];
    __syncthreads();
    int t = blockIdx.x * 256 + threadIdx.x;
    int vi = t >> 3;                   // sorted node index
    int j = threadIdx.x & 7;           // feature octet
    int w = threadIdx.x >> 3;          // group in block
    const h8* na8 = (const h8*)nodearr;
    const _Float16* tbsj = tbs + j * 8;
    h8 acc = {};
    int v = 0;
    bool valid = vi < N;
    if (valid) {
        int2 s2 = srt[vi];
        int e = s2.x;
        v = (int)((unsigned)s2.y & 0x1FFFFu);
        int end = e + (int)((unsigned)s2.y >> 17);
        for (; e + 7 < end; e += 8) {
            unsigned q0 = packed[e],     q1 = packed[e + 1], q2 = packed[e + 2], q3 = packed[e + 3];
            unsigned q4 = packed[e + 4], q5 = packed[e + 5], q6 = packed[e + 6], q7 = packed[e + 7];
            h8 m0 = na8[(q0 & 0x1FFFFu) * 8 + j];
            h8 m1 = na8[(q1 & 0x1FFFFu) * 8 + j];
            h8 m2 = na8[(q2 & 0x1FFFFu) * 8 + j];
            h8 m3 = na8[(q3 & 0x1FFFFu) * 8 + j];
            h8 m4 = na8[(q4 & 0x1FFFFu) * 8 + j];
            h8 m5 = na8[(q5 & 0x1FFFFu) * 8 + j];
            h8 m6 = na8[(q6 & 0x1FFFFu) * 8 + j];
            h8 m7 = na8[(q7 & 0x1FFFFu) * 8 + j];
            h8 t0 = *(const h8*)&tbsj[(q0 >> 17) * 64];
            h8 t1 = *(const h8*)&tbsj[(q1 >> 17) * 64];
            h8 t2 = *(const h8*)&tbsj[(q2 >> 17) * 64];
            h8 t3 = *(const h8*)&tbsj[(q3 >> 17) * 64];
            h8 t4 = *(const h8*)&tbsj[(q4 >> 17) * 64];
            h8 t5 = *(const h8*)&tbsj[(q5 >> 17) * 64];
            h8 t6 = *(const h8*)&tbsj[(q6 >> 17) * 64];
            h8 t7 = *(const h8*)&tbsj[(q7 >> 17) * 64];
            h8 s0 = relu8(m0 + t0), s1 = relu8(m1 + t1);
            h8 s2v = relu8(m2 + t2), s3 = relu8(m3 + t3);
            h8 s4 = relu8(m4 + t4), s5 = relu8(m5 + t5);
            h8 s6 = relu8(m6 + t6), s7 = relu8(m7 + t7);
            acc += ((s0 + s1) + (s2v + s3)) + ((s4 + s5) + (s6 + s7));
        }
        for (; e < end; ++e) {
            unsigned q0 = packed[e];
            h8 m0 = na8[(q0 & 0x1FFFFu) * 8 + j];
            h8 t0 = *(const h8*)&tbsj[(q0 >> 17) * 64];
            acc += relu8(m0 + t0);
        }
    }
    if (FINAL) {
        if (valid) ((h8*)out)[(long long)v * 8 + j] = acc;
        return;
    }
    *(h8*)&rowb[w][j * 8] = acc;
    __syncthreads();
    if (!valid) return;
    const h2* rp = (const h2*)&rowb[w][0];
    const unsigned* wj = wst + j * 8;
    float o0 = 0.f, o1 = 0.f, o2 = 0.f, o3 = 0.f, o4 = 0.f, o5 = 0.f, o6 = 0.f, o7 = 0.f;
#pragma unroll
    for (int k2 = 0; k2 < 32; ++k2) {
        h2 r = rp[k2];
        uint4 wa = *(const uint4*)&wj[k2 * 64];
        uint4 wb = *(const uint4*)&wj[k2 * 64 + 4];
        o0 = __builtin_amdgcn_fdot2(r, u2h(wa.x), o0, false);
        o1 = __builtin_amdgcn_fdot2(r, u2h(wa.y), o1, false);
        o2 = __builtin_amdgcn_fdot2(r, u2h(wa.z), o2, false);
        o3 = __builtin_amdgcn_fdot2(r, u2h(wa.w), o3, false);
        o4 = __builtin_amdgcn_fdot2(r, u2h(wb.x), o4, false);
        o5 = __builtin_amdgcn_fdot2(r, u2h(wb.y), o5, false);
        o6 = __builtin_amdgcn_fdot2(r, u2h(wb.z), o6, false);
        o7 = __builtin_amdgcn_fdot2(r, u2h(wb.w), o7, false);
    }
    h8 ta = ((const h8*)tAu)[x[v] * 8 + j];
    h8 o;
    o[0] = (_Float16)(o0 + (float)ta[0]); o[1] = (_Float16)(o1 + (float)ta[1]);
    o[2] = (_Float16)(o2 + (float)ta[2]); o[3] = (_Float16)(o3 + (float)ta[3]);
    o[4] = (_Float16)(o4 + (float)ta[4]); o[5] = (_Float16)(o5 + (float)ta[5]);
    o[6] = (_Float16)(o6 + (float)ta[6]); o[7] = (_Float16)(o7 + (float)ta[7]);
    ((h8*)out)[(long long)v * 8 + j] = o;
}

// batch is sorted: run-length accumulate, flush on mol change. 16 lanes x h4 per 32-node chunk.
__global__ void mol_pool_kernel(const _Float16* __restrict__ ns, const int* __restrict__ batch,
                                float* __restrict__ mol, int N) {
    int g = (blockIdx.x * blockDim.x + threadIdx.x) >> 4;
    int j = threadIdx.x & 15;
    int n0 = g * 32;
    if (n0 >= N) return;
    int n1 = min(n0 + 32, N);
    const h4* ns4 = (const h4*)ns;
    int cur = batch[n0];
    float ax = 0.f, ay = 0.f, az = 0.f, aw = 0.f;
    for (int n = n0; n < n1; ++n) {
        int b = batch[n];
        if (b != cur) {
            float* mp = &mol[(long long)cur * 64 + j * 4];
            atomicAdd(mp + 0, ax); atomicAdd(mp + 1, ay);
            atomicAdd(mp + 2, az); atomicAdd(mp + 3, aw);
            ax = ay = az = aw = 0.f; cur = b;
        }
        h4 vv = ns4[(long long)n * 16 + j];
        ax += (float)vv.x; ay += (float)vv.y; az += (float)vv.z; aw += (float)vv.w;
    }
    float* mp = &mol[(long long)cur * 64 + j * 4];
    atomicAdd(mp + 0, ax); atomicAdd(mp + 1, ay);
    atomicAdd(mp + 2, az); atomicAdd(mp + 3, aw);
}

__global__ void head_kernel(const float* __restrict__ mol, const float* __restrict__ W1,
                            const float* __restrict__ b1, const float* __restrict__ W2,
                            const float* __restrict__ b2, float* __restrict__ out) {
    int g = blockIdx.x;
    int j = threadIdx.x;   // 0..127
    float s = b1[j];
#pragma unroll
    for (int k = 0; k < 64; ++k) s = fmaf(mol[g * 64 + k], W1[k * 128 + j], s);
    s = fmaxf(s, 0.0f) * W2[j];
    __shared__ float red[128];
    red[j] = s;
    __syncthreads();
    for (int off = 64; off > 0; off >>= 1) {
        if (j < off) red[j] += red[j + off];
        __syncthreads();
    }
    if (j == 0) out[g] = red[0] + b2[0];
}

extern "C" void kernel_launch(void* const* d_in, const int* in_sizes, int n_in,
                              void* d_out, int out_size, void* d_ws, size_t ws_size,
                              hipStream_t stream) {
    const int*   x          = (const int*)d_in[0];
    const int*   eattr      = (const int*)d_in[1];
    const int*   ei         = (const int*)d_in[2];
    const int*   batch      = (const int*)d_in[3];
    const float* atom_table = (const float*)d_in[4];
    const float* bond_table = (const float*)d_in[5];
    const float* Wi         = (const float*)d_in[6];
    const float* bi         = (const float*)d_in[7];
    const float* Wu         = (const float*)d_in[8];
    const float* bu         = (const float*)d_in[9];
    const float* W1         = (const float*)d_in[10];
    const float* b1         = (const float*)d_in[11];
    const float* W2         = (const float*)d_in[12];
    const float* b2         = (const float*)d_in[13];

    const int N = in_sizes[0];      // 100000
    const int E = in_sizes[1];      // 1600000
    const int M = out_size;         // 2048
    const int AR = in_sizes[4] / 64;                             // 119 atom rows
    const int K = (N + (1 << SLICE_SHIFT) - 1) >> SLICE_SHIFT;   // 98 slices

    char* ws = (char*)d_ws;
    size_t off_b = 0;
    auto alloc = [&](size_t bytes) -> void* {
        void* p = ws + off_b;
        off_b = (off_b + bytes + 255) & ~(size_t)255;
        return p;
    };
    size_t nbytes = (size_t)N * MSG * 2;             // 12.8 MB
    size_t abytes = (size_t)K * CAP_E * 8;           // 16.1 MB (fixed-cap aux)
    _Float16* bufA  = (_Float16*)alloc(nbytes);
    _Float16* bufB  = (_Float16*)alloc(nbytes > abytes ? nbytes : abytes);  // aliased w/ aux
    _Float16* bufC  = (_Float16*)alloc(nbytes);
    unsigned long long* aux = (unsigned long long*)bufB;   // dead before bufB first written
    unsigned* packed = (unsigned*)alloc((size_t)K * CAP_E * 4);   // 8 MB, fixed-cap
    int*      nstart = (int*)alloc((size_t)N * 4);
    int*      ndeg   = (int*)alloc((size_t)N * 4);
    int2*     srt    = (int2*)alloc((size_t)N * 8);
    int*      bucket = (int*)alloc((size_t)NBIN * CAP_B * 4);     // 4 MB
    int*      bcnt   = (int*)alloc((size_t)NBIN * 4);
    int*      bbase  = (int*)alloc((size_t)NBIN * 4);
    int*      gcur   = (int*)alloc((size_t)MAXSLICES * 4);
    _Float16* tAi    = (_Float16*)alloc((size_t)AR * MSG * 2);
    _Float16* tBi    = (_Float16*)alloc((size_t)4 * MSG * 2);
    _Float16* tAu    = (_Float16*)alloc((size_t)AR * MSG * 2);
    _Float16* tBu    = (_Float16*)alloc((size_t)4 * MSG * 2);
    unsigned* wstb   = (unsigned*)alloc((size_t)32 * 64 * 4);
    float*    mol    = (float*)alloc((size_t)M * MSG * 4);
    (void)ws_size; (void)n_in;

    // Tables: tA (119x64 atom term), tB (4x64 bond term + bias), wst (fp16-pair Wagg).
    const float* Wagg = Wu + 80 * MSG;
    build_tabA_kernel<<<(AR * MSG + 255) / 256, 256, 0, stream>>>(atom_table, Wi, tAi, AR);
    build_tabB_kernel<<<1, 256, 0, stream>>>(bond_table, Wi + 64 * MSG, bi, tBi);
    build_tabA_kernel<<<(AR * MSG + 255) / 256, 256, 0, stream>>>(atom_table, Wu, tAu, AR);
    build_tabB_kernel<<<1, 256, 0, stream>>>(bond_table, Wu + 64 * MSG, bu, tBu);
    build_tabW_kernel<<<8, 256, 0, stream>>>(Wagg, wstb);
    node_init_kernel<<<(int)(((long long)N * 8 + 255) / 256), 256, 0, stream>>>(x, tAi, bufC, N);

    // ---- CSR by dst (fixed-cap slices): partition -> place (nstart/ndeg + packed) ----
    ginit_kernel<<<1, MAXSLICES, 0, stream>>>(gcur, K);
    partition_kernel<<<(E + 1023) / 1024, 256, 0, stream>>>(ei, eattr, E, gcur, aux, K);
    place_kernel<<<K, 1024, 0, stream>>>(aux, gcur, nstart, ndeg, packed, N);

    // ---- degree sort: bucket partition -> scan -> compact (srt) ----
    hipMemsetAsync(bcnt, 0, (size_t)NBIN * 4, stream);
    dbin_kernel<<<(N + 255) / 256, 256, 0, stream>>>(ndeg, N, bcnt, bucket);
    bscan_kernel<<<1, 64, 0, stream>>>(bcnt, bbase);
    compact_kernel<<<NBIN, 256, 0, stream>>>(bucket, bcnt, bbase, nstart, ndeg, srt);

    // ---- message passes: degree-sorted, single row-gather per edge, dot2 epilogue ----
    const int gblocks = (int)(((long long)N * 8 + 255) / 256);
    gather_kernel<false><<<gblocks, 256, 0, stream>>>(packed, srt, bufC, tBi, wstb, tAu, x, bufA, N);
    gather_kernel<false><<<gblocks, 256, 0, stream>>>(packed, srt, bufA, tBu, wstb, tAu, x, bufB, N);
    gather_kernel<false><<<gblocks, 256, 0, stream>>>(packed, srt, bufB, tBu, wstb, tAu, x, bufA, N);
    gather_kernel<false><<<gblocks, 256, 0, stream>>>(packed, srt, bufA, tBu, wstb, tAu, x, bufB, N);
    gather_kernel<true><<<gblocks, 256, 0, stream>>>(packed, srt, bufB, tBu, nullptr, nullptr, nullptr, bufA, N);

    // ---- readout ----
    hipMemsetAsync(mol, 0, (size_t)M * MSG * 4, stream);
    mol_pool_kernel<<<(((N + 31) / 32) * 16 + 255) / 256, 256, 0, stream>>>(bufA, batch, mol, N);
    head_kernel<<<M, 128, 0, stream>>>(mol, W1, b1, W2, b2, (float*)d_out);
}

// Round 12
// 304.260 us; speedup vs baseline: 1.6982x; 1.0307x over previous
//
#include <hip/hip_runtime.h>

#define MSG 64
#define SLICE_SHIFT 10     // 1024 nodes per slice
#define MAXSLICES 128
#define REP 8              // cursor replicas per slice (contention /8)
#define CAP_R 3072         // edges per (slice,rep) region (mean 2048, +22 sigma)
#define CAP_E 20480        // packed edges per slice (mean 16384, +32 sigma)
#define CAP_B 16384        // nodes per degree bucket
#define NBIN 64

typedef _Float16 h2 __attribute__((ext_vector_type(2)));
typedef _Float16 h4 __attribute__((ext_vector_type(4)));
typedef _Float16 h8 __attribute__((ext_vector_type(8)));

__device__ inline h8 relu8(h8 v) {
    h8 z = {};
    return __builtin_elementwise_max(v, z);
}

__device__ inline h2 u2h(unsigned u) { union { unsigned u; h2 h; } c; c.u = u; return c.h; }

// Fused setup: role-switched on blockIdx.
// [0,ab): tAi  [ab]: tBi  [ab+1, 2ab+1): tAu  [2ab+1]: tBu  [2ab+2, 2ab+10): wst  [2ab+10]: gcur
__global__ void setup_kernel(const float* __restrict__ atom, const float* __restrict__ bond,
                             const float* __restrict__ Wi, const float* __restrict__ bi,
                             const float* __restrict__ Wu, const float* __restrict__ bu,
                             const float* __restrict__ Wagg,
                             _Float16* __restrict__ tAi, _Float16* __restrict__ tBi,
                             _Float16* __restrict__ tAu, _Float16* __restrict__ tBu,
                             unsigned* __restrict__ wst, int* __restrict__ gcur,
                             int AR, int K, int ab) {
    int b = blockIdx.x;
    if (b < 2 * ab + 2) {
        bool upd = b >= ab + 1;
        const float* W = upd ? Wu : Wi;
        int lb = upd ? b - (ab + 1) : b;
        if (lb < ab) {   // tabA
            _Float16* tA = upd ? tAu : tAi;
            int t = lb * 256 + threadIdx.x;
            if (t < AR * MSG) {
                int i = t & 63, a = t >> 6;
                float s = 0.f;
                for (int k = 0; k < 64; ++k) s = fmaf(atom[a * 64 + k], W[k * 64 + i], s);
                tA[t] = (_Float16)s;
            }
        } else {         // tabB
            _Float16* tBo = upd ? tBu : tBi;
            const float* bias = upd ? bu : bi;
            const float* W16 = W + 64 * MSG;
            int t = threadIdx.x;
            int i = t & 63, r = t >> 6;
            float s = bias[i];
            for (int k = 0; k < 16; ++k) s = fmaf(bond[r * 16 + k], W16[k * 64 + i], s);
            tBo[t] = (_Float16)s;
        }
    } else if (b < 2 * ab + 10) {   // wst: fp16-pair Wagg for v_dot2
        int t = (b - (2 * ab + 2)) * 256 + threadIdx.x;
        if (t < 2048) {
            int k2 = t >> 6, c = t & 63;
            h2 h; h[0] = (_Float16)Wagg[(2 * k2) * 64 + c]; h[1] = (_Float16)Wagg[(2 * k2 + 1) * 64 + c];
            union { h2 h; unsigned u; } cv; cv.h = h;
            wst[k2 * 64 + c] = cv.u;
        }
    } else {                        // gcur init (replicated fixed-cap regions)
        for (int q = threadIdx.x; q < K * REP; q += 256) gcur[q] = q * CAP_R;
    }
}

// bufC[v] = tAi[x[v]]  (node-level atom-term table for pass 0)
__global__ void node_init_kernel(const int* __restrict__ x, const _Float16* __restrict__ tA,
                                 _Float16* __restrict__ bufC, int N) {
    int t = blockIdx.x * blockDim.x + threadIdx.x;
    int v = t >> 3, j = t & 7;
    if (v < N) ((h8*)bufC)[(long long)v * 8 + j] = ((const h8*)tA)[x[v] * 8 + j];
}

// Phase 1: radix-partition edges into per-(slice, blockIdx&7) fixed-cap regions.
// Block-local LDS ranking; reservation atomics spread over K*REP words.
// record = pw(19b)<<17 | dst(17b), pw = src | eattr<<17.
__global__ __launch_bounds__(256) void partition_kernel(
    const int* __restrict__ ei, const int* __restrict__ eattr,
    int E, int* __restrict__ gcur, unsigned long long* __restrict__ aux, int K)
{
    __shared__ int cnt[MAXSLICES];
    __shared__ int base[MAXSLICES];
    if (threadIdx.x < MAXSLICES) cnt[threadIdx.x] = 0;
    __syncthreads();
    int rep = blockIdx.x & (REP - 1);
    int e0 = blockIdx.x * 1024;
    int sl0 = -1, sl1 = -1, sl2 = -1, sl3 = -1;
    int rk0 = 0, rk1 = 0, rk2 = 0, rk3 = 0;
    unsigned long long p0 = 0, p1 = 0, p2 = 0, p3 = 0;
    {
        int e = e0 + 0 * 256 + threadIdx.x;
        if (e < E) {
            int s = ei[e], d = ei[E + e];
            p0 = ((unsigned long long)((unsigned)s | ((unsigned)eattr[e] << 17)) << 17) | (unsigned)d;
            sl0 = d >> SLICE_SHIFT; rk0 = atomicAdd(&cnt[sl0], 1);
        }
    }
    {
        int e = e0 + 1 * 256 + threadIdx.x;
        if (e < E) {
            int s = ei[e], d = ei[E + e];
            p1 = ((unsigned long long)((unsigned)s | ((unsigned)eattr[e] << 17)) << 17) | (unsigned)d;
            sl1 = d >> SLICE_SHIFT; rk1 = atomicAdd(&cnt[sl1], 1);
        }
    }
    {
        int e = e0 + 2 * 256 + threadIdx.x;
        if (e < E) {
            int s = ei[e], d = ei[E + e];
            p2 = ((unsigned long long)((unsigned)s | ((unsigned)eattr[e] << 17)) << 17) | (unsigned)d;
            sl2 = d >> SLICE_SHIFT; rk2 = atomicAdd(&cnt[sl2], 1);
        }
    }
    {
        int e = e0 + 3 * 256 + threadIdx.x;
        if (e < E) {
            int s = ei[e], d = ei[E + e];
            p3 = ((unsigned long long)((unsigned)s | ((unsigned)eattr[e] << 17)) << 17) | (unsigned)d;
            sl3 = d >> SLICE_SHIFT; rk3 = atomicAdd(&cnt[sl3], 1);
        }
    }
    __syncthreads();
    if (threadIdx.x < K && cnt[threadIdx.x] > 0)
        base[threadIdx.x] = atomicAdd(&gcur[threadIdx.x * REP + rep], cnt[threadIdx.x]);
    __syncthreads();
    if (sl0 >= 0) aux[base[sl0] + rk0] = p0;
    if (sl1 >= 0) aux[base[sl1] + rk1] = p1;
    if (sl2 >= 0) aux[base[sl2] + rk2] = p2;
    if (sl3 >= 0) aux[base[sl3] + rk3] = p3;
}

// Phase 2: one block OWNS one slice (8 region fragments). Pass A: count dsts in
// LDS, block-scan -> per-node start/deg. Pass B: place records via LDS cursors.
__global__ __launch_bounds__(1024) void place_kernel(
    const unsigned long long* __restrict__ aux, const int* __restrict__ gcur,
    int* __restrict__ nstart, int* __restrict__ ndeg,
    unsigned* __restrict__ packed, int N)
{
    __shared__ int cnt[1 << SLICE_SHIFT];
    __shared__ int wsum[16];
    int s = blockIdx.x;
    int lo = s << SLICE_SHIFT;
    cnt[threadIdx.x] = 0;
    __syncthreads();
    for (int r = 0; r < REP; ++r) {
        int q = s * REP + r;
        int start = q * CAP_R, end = gcur[q];
        for (int idx = start + threadIdx.x; idx < end; idx += 1024)
            atomicAdd(&cnt[(int)(aux[idx] & 0x1FFFFu) & ((1 << SLICE_SHIFT) - 1)], 1);
    }
    __syncthreads();
    int c = cnt[threadIdx.x];
    int lane = threadIdx.x & 63, w = threadIdx.x >> 6;
    int sc = c;
    for (int off = 1; off < 64; off <<= 1) { int t = __shfl_up(sc, off); if (lane >= off) sc += t; }
    if (lane == 63) wsum[w] = sc;
    __syncthreads();
    if (w == 0 && lane < 16) {
        int t = wsum[lane];
        for (int off = 1; off < 16; off <<= 1) { int u = __shfl_up(t, off); if (lane >= off) t += u; }
        wsum[lane] = t;
    }
    __syncthreads();
    if (w > 0) sc += wsum[w - 1];
    int v = lo + threadIdx.x;
    int st = s * CAP_E + sc - c;
    if (v < N) { nstart[v] = st; ndeg[v] = c; }
    __syncthreads();
    cnt[threadIdx.x] = st;
    __syncthreads();
    for (int r = 0; r < REP; ++r) {
        int q = s * REP + r;
        int start = q * CAP_R, end = gcur[q];
        for (int idx = start + threadIdx.x; idx < end; idx += 1024) {
            unsigned long long a = aux[idx];
            int d = (int)(a & 0x1FFFFu);
            unsigned pw = (unsigned)(a >> 17);
            int p = atomicAdd(&cnt[d & ((1 << SLICE_SHIFT) - 1)], 1);
            packed[p] = pw;
        }
    }
}

// Degree-bucket partition of nodes. bin = min(deg, 63).
__global__ __launch_bounds__(256) void dbin_kernel(const int* __restrict__ ndeg, int N,
                                                   int* __restrict__ bcnt, int* __restrict__ bucket) {
    __shared__ int cnt[NBIN];
    __shared__ int base[NBIN];
    if (threadIdx.x < NBIN) cnt[threadIdx.x] = 0;
    __syncthreads();
    int v = blockIdx.x * 256 + threadIdx.x;
    int b = -1, rk = 0;
    if (v < N) { b = min(ndeg[v], NBIN - 1); rk = atomicAdd(&cnt[b], 1); }
    __syncthreads();
    if (threadIdx.x < NBIN && cnt[threadIdx.x] > 0)
        base[threadIdx.x] = atomicAdd(&bcnt[threadIdx.x], cnt[threadIdx.x]);
    __syncthreads();
    if (b >= 0) bucket[b * CAP_B + base[b] + rk] = v;
}

// Compact buckets -> srt[v'] = {edge_start, v | deg<<17}; inline prefix over bcnt.
__global__ void compact_kernel(const int* __restrict__ bucket, const int* __restrict__ bcnt,
                               const int* __restrict__ nstart, const int* __restrict__ ndeg,
                               int2* __restrict__ srt) {
    __shared__ int sbase;
    int b = blockIdx.x;
    if (threadIdx.x == 0) {
        int run = 0;
        for (int i = 0; i < b; ++i) run += bcnt[i];
        sbase = run;
    }
    __syncthreads();
    int n = bcnt[b], base = sbase;
    for (int i = threadIdx.x; i < n; i += 256) {
        int v = bucket[b * CAP_B + i];
        srt[base + i] = make_int2(nstart[v], v | (ndeg[v] << 17));
    }
}

// 8 lanes per node (h8 = 16B per lane), 32 nodes per 256-thread block, nodes in
// DEGREE-SORTED order via srt. acc = sum_{in-edges} relu(nodearr[src] + tB[ea]);
// tB in 512B LDS; epilogue GEMM via v_dot2_f32_f16.
// !FINAL: out[v]=(acc@Wagg)+tAu[x[v]];  FINAL: out[v]=acc.
template <bool FINAL>
__global__ __launch_bounds__(256, 8) void gather_kernel(
    const unsigned* __restrict__ packed, const int2* __restrict__ srt,
    const _Float16* __restrict__ nodearr, const _Float16* __restrict__ tB,
    const unsigned* __restrict__ wst_g, const _Float16* __restrict__ tAu,
    const int* __restrict__ x, _Float16* __restrict__ out, int N)
{
    __shared__ _Float16 tbs[4 * 64];
    __shared__ unsigned wst[32 * 64];
    __shared__ _Float16 rowb[32][72];
    tbs[threadIdx.x] = tB[threadIdx.x];
    if (!FINAL)
        for (int idx = threadIdx.x; idx < 2048; idx += 256) wst[idx] = wst_g[idx];
    __syncthreads();
    int t = blockIdx.x * 256 + threadIdx.x;
    int vi = t >> 3;                   // sorted node index
    int j = threadIdx.x & 7;           // feature octet
    int w = threadIdx.x >> 3;          // group in block
    const h8* na8 = (const h8*)nodearr;
    const _Float16* tbsj = tbs + j * 8;
    h8 acc = {};
    int v = 0;
    bool valid = vi < N;
    if (valid) {
        int2 s2 = srt[vi];
        int e = s2.x;
        v = (int)((unsigned)s2.y & 0x1FFFFu);
        int end = e + (int)((unsigned)s2.y >> 17);
        for (; e + 7 < end; e += 8) {
            unsigned q0 = packed[e],     q1 = packed[e + 1], q2 = packed[e + 2], q3 = packed[e + 3];
            unsigned q4 = packed[e + 4], q5 = packed[e + 5], q6 = packed[e + 6], q7 = packed[e + 7];
            h8 m0 = na8[(q0 & 0x1FFFFu) * 8 + j];
            h8 m1 = na8[(q1 & 0x1FFFFu) * 8 + j];
            h8 m2 = na8[(q2 & 0x1FFFFu) * 8 + j];
            h8 m3 = na8[(q3 & 0x1FFFFu) * 8 + j];
            h8 m4 = na8[(q4 & 0x1FFFFu) * 8 + j];
            h8 m5 = na8[(q5 & 0x1FFFFu) * 8 + j];
            h8 m6 = na8[(q6 & 0x1FFFFu) * 8 + j];
            h8 m7 = na8[(q7 & 0x1FFFFu) * 8 + j];
            h8 t0 = *(const h8*)&tbsj[(q0 >> 17) * 64];
            h8 t1 = *(const h8*)&tbsj[(q1 >> 17) * 64];
            h8 t2 = *(const h8*)&tbsj[(q2 >> 17) * 64];
            h8 t3 = *(const h8*)&tbsj[(q3 >> 17) * 64];
            h8 t4 = *(const h8*)&tbsj[(q4 >> 17) * 64];
            h8 t5 = *(const h8*)&tbsj[(q5 >> 17) * 64];
            h8 t6 = *(const h8*)&tbsj[(q6 >> 17) * 64];
            h8 t7 = *(const h8*)&tbsj[(q7 >> 17) * 64];
            h8 s0 = relu8(m0 + t0), s1 = relu8(m1 + t1);
            h8 s2v = relu8(m2 + t2), s3 = relu8(m3 + t3);
            h8 s4 = relu8(m4 + t4), s5 = relu8(m5 + t5);
            h8 s6 = relu8(m6 + t6), s7 = relu8(m7 + t7);
            acc += ((s0 + s1) + (s2v + s3)) + ((s4 + s5) + (s6 + s7));
        }
        for (; e < end; ++e) {
            unsigned q0 = packed[e];
            h8 m0 = na8[(q0 & 0x1FFFFu) * 8 + j];
            h8 t0 = *(const h8*)&tbsj[(q0 >> 17) * 64];
            acc += relu8(m0 + t0);
        }
    }
    if (FINAL) {
        if (valid) ((h8*)out)[(long long)v * 8 + j] = acc;
        return;
    }
    *(h8*)&rowb[w][j * 8] = acc;
    __syncthreads();
    if (!valid) return;
    const h2* rp = (const h2*)&rowb[w][0];
    const unsigned* wj = wst + j * 8;
    float o0 = 0.f, o1 = 0.f, o2 = 0.f, o3 = 0.f, o4 = 0.f, o5 = 0.f, o6 = 0.f, o7 = 0.f;
#pragma unroll
    for (int k2 = 0; k2 < 32; ++k2) {
        h2 r = rp[k2];
        uint4 wa = *(const uint4*)&wj[k2 * 64];
        uint4 wb = *(const uint4*)&wj[k2 * 64 + 4];
        o0 = __builtin_amdgcn_fdot2(r, u2h(wa.x), o0, false);
        o1 = __builtin_amdgcn_fdot2(r, u2h(wa.y), o1, false);
        o2 = __builtin_amdgcn_fdot2(r, u2h(wa.z), o2, false);
        o3 = __builtin_amdgcn_fdot2(r, u2h(wa.w), o3, false);
        o4 = __builtin_amdgcn_fdot2(r, u2h(wb.x), o4, false);
        o5 = __builtin_amdgcn_fdot2(r, u2h(wb.y), o5, false);
        o6 = __builtin_amdgcn_fdot2(r, u2h(wb.z), o6, false);
        o7 = __builtin_amdgcn_fdot2(r, u2h(wb.w), o7, false);
    }
    h8 ta = ((const h8*)tAu)[x[v] * 8 + j];
    h8 o;
    o[0] = (_Float16)(o0 + (float)ta[0]); o[1] = (_Float16)(o1 + (float)ta[1]);
    o[2] = (_Float16)(o2 + (float)ta[2]); o[3] = (_Float16)(o3 + (float)ta[3]);
    o[4] = (_Float16)(o4 + (float)ta[4]); o[5] = (_Float16)(o5 + (float)ta[5]);
    o[6] = (_Float16)(o6 + (float)ta[6]); o[7] = (_Float16)(o7 + (float)ta[7]);
    ((h8*)out)[(long long)v * 8 + j] = o;
}

// batch is sorted: run-length accumulate, flush on mol change. 16 lanes x h4 per 32-node chunk.
__global__ void mol_pool_kernel(const _Float16* __restrict__ ns, const int* __restrict__ batch,
                                float* __restrict__ mol, int N) {
    int g = (blockIdx.x * blockDim.x + threadIdx.x) >> 4;
    int j = threadIdx.x & 15;
    int n0 = g * 32;
    if (n0 >= N) return;
    int n1 = min(n0 + 32, N);
    const h4* ns4 = (const h4*)ns;
    int cur = batch[n0];
    float ax = 0.f, ay = 0.f, az = 0.f, aw = 0.f;
    for (int n = n0; n < n1; ++n) {
        int b = batch[n];
        if (b != cur) {
            float* mp = &mol[(long long)cur * 64 + j * 4];
            atomicAdd(mp + 0, ax); atomicAdd(mp + 1, ay);
            atomicAdd(mp + 2, az); atomicAdd(mp + 3, aw);
            ax = ay = az = aw = 0.f; cur = b;
        }
        h4 vv = ns4[(long long)n * 16 + j];
        ax += (float)vv.x; ay += (float)vv.y; az += (float)vv.z; aw += (float)vv.w;
    }
    float* mp = &mol[(long long)cur * 64 + j * 4];
    atomicAdd(mp + 0, ax); atomicAdd(mp + 1, ay);
    atomicAdd(mp + 2, az); atomicAdd(mp + 3, aw);
}

__global__ void head_kernel(const float* __restrict__ mol, const float* __restrict__ W1,
                            const float* __restrict__ b1, const float* __restrict__ W2,
                            const float* __restrict__ b2, float* __restrict__ out) {
    int g = blockIdx.x;
    int j = threadIdx.x;   // 0..127
    float s = b1[j];
#pragma unroll
    for (int k = 0; k < 64; ++k) s = fmaf(mol[g * 64 + k], W1[k * 128 + j], s);
    s = fmaxf(s, 0.0f) * W2[j];
    __shared__ float red[128];
    red[j] = s;
    __syncthreads();
    for (int off = 64; off > 0; off >>= 1) {
        if (j < off) red[j] += red[j + off];
        __syncthreads();
    }
    if (j == 0) out[g] = red[0] + b2[0];
}

extern "C" void kernel_launch(void* const* d_in, const int* in_sizes, int n_in,
                              void* d_out, int out_size, void* d_ws, size_t ws_size,
                              hipStream_t stream) {
    const int*   x          = (const int*)d_in[0];
    const int*   eattr      = (const int*)d_in[1];
    const int*   ei         = (const int*)d_in[2];
    const int*   batch      = (const int*)d_in[3];
    const float* atom_table = (const float*)d_in[4];
    const float* bond_table = (const float*)d_in[5];
    const float* Wi         = (const float*)d_in[6];
    const float* bi         = (const float*)d_in[7];
    const float* Wu         = (const float*)d_in[8];
    const float* bu         = (const float*)d_in[9];
    const float* W1         = (const float*)d_in[10];
    const float* b1         = (const float*)d_in[11];
    const float* W2         = (const float*)d_in[12];
    const float* b2         = (const float*)d_in[13];

    const int N = in_sizes[0];      // 100000
    const int E = in_sizes[1];      // 1600000
    const int M = out_size;         // 2048
    const int AR = in_sizes[4] / 64;                             // 119 atom rows
    const int K = (N + (1 << SLICE_SHIFT) - 1) >> SLICE_SHIFT;   // 98 slices
    const int ab = (AR * MSG + 255) / 256;                       // 30 blocks per tabA

    char* ws = (char*)d_ws;
    size_t off_b = 0;
    auto alloc = [&](size_t bytes) -> void* {
        void* p = ws + off_b;
        off_b = (off_b + bytes + 255) & ~(size_t)255;
        return p;
    };
    size_t nbytes = (size_t)N * MSG * 2;                 // 12.8 MB
    size_t abytes = (size_t)K * REP * CAP_R * 8;         // 19.3 MB (replicated fixed-cap aux)
    _Float16* bufA  = (_Float16*)alloc(nbytes);
    _Float16* bufB  = (_Float16*)alloc(nbytes > abytes ? nbytes : abytes);  // aliased w/ aux
    _Float16* bufC  = (_Float16*)alloc(nbytes);
    unsigned long long* aux = (unsigned long long*)bufB;   // dead before bufB first written
    unsigned* packed = (unsigned*)alloc((size_t)K * CAP_E * 4);   // 8 MB
    int*      nstart = (int*)alloc((size_t)N * 4);
    int*      ndeg   = (int*)alloc((size_t)N * 4);
    int2*     srt    = (int2*)alloc((size_t)N * 8);
    int*      bucket = (int*)alloc((size_t)NBIN * CAP_B * 4);     // 4 MB
    int*      bcnt   = (int*)alloc((size_t)NBIN * 4);
    int*      gcur   = (int*)alloc((size_t)MAXSLICES * REP * 4);
    _Float16* tAi    = (_Float16*)alloc((size_t)AR * MSG * 2);
    _Float16* tBi    = (_Float16*)alloc((size_t)4 * MSG * 2);
    _Float16* tAu    = (_Float16*)alloc((size_t)AR * MSG * 2);
    _Float16* tBu    = (_Float16*)alloc((size_t)4 * MSG * 2);
    unsigned* wstb   = (unsigned*)alloc((size_t)32 * 64 * 4);
    float*    mol    = (float*)alloc((size_t)M * MSG * 4);
    (void)ws_size; (void)n_in;

    const float* Wagg = Wu + 80 * MSG;

    // ---- fused setup: tables + wst + gcur ----
    setup_kernel<<<2 * ab + 11, 256, 0, stream>>>(atom_table, bond_table, Wi, bi, Wu, bu, Wagg,
                                                  tAi, tBi, tAu, tBu, wstb, gcur, AR, K, ab);
    node_init_kernel<<<(int)(((long long)N * 8 + 255) / 256), 256, 0, stream>>>(x, tAi, bufC, N);

    // ---- CSR by dst: partition (replicated cursors) -> place (nstart/ndeg + packed) ----
    partition_kernel<<<(E + 1023) / 1024, 256, 0, stream>>>(ei, eattr, E, gcur, aux, K);
    place_kernel<<<K, 1024, 0, stream>>>(aux, gcur, nstart, ndeg, packed, N);

    // ---- degree sort: bucket partition -> compact (srt) ----
    hipMemsetAsync(bcnt, 0, (size_t)NBIN * 4, stream);
    dbin_kernel<<<(N + 255) / 256, 256, 0, stream>>>(ndeg, N, bcnt, bucket);
    compact_kernel<<<NBIN, 256, 0, stream>>>(bucket, bcnt, nstart, ndeg, srt);

    // ---- message passes: degree-sorted, single row-gather per edge, dot2 epilogue ----
    const int gblocks = (int)(((long long)N * 8 + 255) / 256);
    gather_kernel<false><<<gblocks, 256, 0, stream>>>(packed, srt, bufC, tBi, wstb, tAu, x, bufA, N);
    gather_kernel<false><<<gblocks, 256, 0, stream>>>(packed, srt, bufA, tBu, wstb, tAu, x, bufB, N);
    gather_kernel<false><<<gblocks, 256, 0, stream>>>(packed, srt, bufB, tBu, wstb, tAu, x, bufA, N);
    gather_kernel<false><<<gblocks, 256, 0, stream>>>(packed, srt, bufA, tBu, wstb, tAu, x, bufB, N);
    gather_kernel<true><<<gblocks, 256, 0, stream>>>(packed, srt, bufB, tBu, nullptr, nullptr, nullptr, bufA, N);

    // ---- readout ----
    hipMemsetAsync(mol, 0, (size_t)M * MSG * 4, stream);
    mol_pool_kernel<<<(((N + 31) / 32) * 16 + 255) / 256, 256, 0, stream>>>(bufA, batch, mol, N);
    head_kernel<<<M, 128, 0, stream>>>(mol, W1, b1, W2, b2, (float*)d_out);
}

// Round 13
// 287.020 us; speedup vs baseline: 1.8002x; 1.0601x over previous
//
#include <hip/hip_runtime.h>

#define MSG 64
#define SLICE_SHIFT 9      // 512 nodes per slice
#define SLICE_N (1 << SLICE_SHIFT)
#define MAXSLICES 256
#define REP 8              // cursor replicas per slice
#define CAP_R 1536         // edges per (slice,rep) aux region (mean 1024)
#define CAP_E 12288        // packed edges per slice (mean 8192, +45 sigma)
#define CAP_B 16384        // nodes per degree bucket
#define NBIN 64

typedef _Float16 h2 __attribute__((ext_vector_type(2)));
typedef _Float16 h4 __attribute__((ext_vector_type(4)));
typedef _Float16 h8 __attribute__((ext_vector_type(8)));

__device__ inline h8 relu8(h8 v) {
    h8 z = {};
    return __builtin_elementwise_max(v, z);
}

__device__ inline h2 u2h(unsigned u) { union { unsigned u; h2 h; } c; c.u = u; return c.h; }

// Fused setup, role-switched on blockIdx:
// [0,ab): tAi  [ab]: tBi  [ab+1,2ab+1): tAu  [2ab+1]: tBu  [2ab+2,2ab+10): wst
// [2ab+10]: gcur + bcnt   [2ab+11, 2ab+11+128): mol zero
__global__ void setup_kernel(const float* __restrict__ atom, const float* __restrict__ bond,
                             const float* __restrict__ Wi, const float* __restrict__ bi,
                             const float* __restrict__ Wu, const float* __restrict__ bu,
                             const float* __restrict__ Wagg,
                             _Float16* __restrict__ tAi, _Float16* __restrict__ tBi,
                             _Float16* __restrict__ tAu, _Float16* __restrict__ tBu,
                             unsigned* __restrict__ wst, int* __restrict__ gcur,
                             int* __restrict__ bcnt, float* __restrict__ mol,
                             int AR, int K, int ab) {
    int b = blockIdx.x;
    if (b < 2 * ab + 2) {
        bool upd = b >= ab + 1;
        const float* W = upd ? Wu : Wi;
        int lb = upd ? b - (ab + 1) : b;
        if (lb < ab) {
            _Float16* tA = upd ? tAu : tAi;
            int t = lb * 256 + threadIdx.x;
            if (t < AR * MSG) {
                int i = t & 63, a = t >> 6;
                float s = 0.f;
                for (int k = 0; k < 64; ++k) s = fmaf(atom[a * 64 + k], W[k * 64 + i], s);
                tA[t] = (_Float16)s;
            }
        } else {
            _Float16* tBo = upd ? tBu : tBi;
            const float* bias = upd ? bu : bi;
            const float* W16 = W + 64 * MSG;
            int t = threadIdx.x;
            int i = t & 63, r = t >> 6;
            float s = bias[i];
            for (int k = 0; k < 16; ++k) s = fmaf(bond[r * 16 + k], W16[k * 64 + i], s);
            tBo[t] = (_Float16)s;
        }
    } else if (b < 2 * ab + 10) {
        int t = (b - (2 * ab + 2)) * 256 + threadIdx.x;
        if (t < 2048) {
            int k2 = t >> 6, c = t & 63;
            h2 h; h[0] = (_Float16)Wagg[(2 * k2) * 64 + c]; h[1] = (_Float16)Wagg[(2 * k2 + 1) * 64 + c];
            union { h2 h; unsigned u; } cv; cv.h = h;
            wst[k2 * 64 + c] = cv.u;
        }
    } else if (b == 2 * ab + 10) {
        for (int q = threadIdx.x; q < K * REP; q += 256) gcur[q] = q * CAP_R;
        if (threadIdx.x < NBIN) bcnt[threadIdx.x] = 0;
    } else {
        int t = (b - (2 * ab + 11)) * 256 + threadIdx.x;   // 128 blocks x 256 x 16B = 512KB
        ((float4*)mol)[t] = make_float4(0.f, 0.f, 0.f, 0.f);
    }
}

// bufC[v] = tAi[x[v]]
__global__ void node_init_kernel(const int* __restrict__ x, const _Float16* __restrict__ tA,
                                 _Float16* __restrict__ bufC, int N) {
    int t = blockIdx.x * blockDim.x + threadIdx.x;
    int v = t >> 3, j = t & 7;
    if (v < N) ((h8*)bufC)[(long long)v * 8 + j] = ((const h8*)tA)[x[v] * 8 + j];
}

// Phase 1: radix-partition with LDS RUN-STAGING for coalesced aux writes.
// record = pw(19b)<<17 | dst(17b), pw = src | eattr<<17.  slice = dst>>9.
__global__ __launch_bounds__(256) void partition_kernel(
    const int* __restrict__ ei, const int* __restrict__ eattr,
    int E, int* __restrict__ gcur, unsigned long long* __restrict__ aux, int K)
{
    __shared__ int cnt[MAXSLICES];
    __shared__ int lexcl[MAXSLICES];
    __shared__ int gbase[MAXSLICES];
    __shared__ int wsum[4];
    __shared__ unsigned long long stage[1024];
    if (threadIdx.x < MAXSLICES) cnt[threadIdx.x] = 0;
    __syncthreads();
    int rep = blockIdx.x & (REP - 1);
    int e0 = blockIdx.x * 1024;
    int total = min(1024, E - e0);
    int sl[4]; int rk[4]; unsigned long long rec[4];
#pragma unroll
    for (int r = 0; r < 4; ++r) {
        sl[r] = -1;
        int e = e0 + r * 256 + threadIdx.x;
        if (e < E) {
            int s = ei[e], d = ei[E + e];
            rec[r] = ((unsigned long long)((unsigned)s | ((unsigned)eattr[e] << 17)) << 17) | (unsigned)d;
            sl[r] = d >> SLICE_SHIFT;
            rk[r] = atomicAdd(&cnt[sl[r]], 1);
        }
    }
    __syncthreads();
    // exclusive scan of cnt[256] with 256 threads + global reservation
    {
        int c = cnt[threadIdx.x];
        int lane = threadIdx.x & 63, w = threadIdx.x >> 6;
        int sc = c;
        for (int off = 1; off < 64; off <<= 1) { int t = __shfl_up(sc, off); if (lane >= off) sc += t; }
        if (lane == 63) wsum[w] = sc;
        __syncthreads();
        int add = 0;
        for (int q = 0; q < 3; ++q) if (w > q) add += wsum[q];
        lexcl[threadIdx.x] = sc + add - c;
        if (threadIdx.x < K && c > 0)
            gbase[threadIdx.x] = atomicAdd(&gcur[threadIdx.x * REP + rep], c);
    }
    __syncthreads();
#pragma unroll
    for (int r = 0; r < 4; ++r)
        if (sl[r] >= 0) stage[lexcl[sl[r]] + rk[r]] = rec[r];
    __syncthreads();
    // write runs: consecutive tid -> consecutive positions within per-slice runs
#pragma unroll
    for (int r = 0; r < 4; ++r) {
        int i = r * 256 + threadIdx.x;
        if (i < total) {
            unsigned long long a = stage[i];
            int s = (int)((unsigned)a & 0x1FFFFu) >> SLICE_SHIFT;
            aux[gbase[s] + (i - lexcl[s])] = a;
        }
    }
}

// Phase 2: one block OWNS one slice. Pass A: count + scan -> nstart/ndeg.
// Pass B: scatter pw into LDS stage at final relative position.
// Pass C: stream stage out linearly (fully coalesced packed writes).
__global__ __launch_bounds__(1024) void place_kernel(
    const unsigned long long* __restrict__ aux, const int* __restrict__ gcur,
    int* __restrict__ nstart, int* __restrict__ ndeg,
    unsigned* __restrict__ packed, int N)
{
    __shared__ int cnt[SLICE_N];
    __shared__ int wsum[8];
    __shared__ unsigned stage[CAP_E];
    int s = blockIdx.x;
    int lo = s << SLICE_SHIFT;
    if (threadIdx.x < SLICE_N) cnt[threadIdx.x] = 0;
    __syncthreads();
    for (int r = 0; r < REP; ++r) {
        int q = s * REP + r;
        int start = q * CAP_R, end = gcur[q];
        for (int idx = start + threadIdx.x; idx < end; idx += 1024)
            atomicAdd(&cnt[(int)(aux[idx] & 0x1FFFFu) & (SLICE_N - 1)], 1);
    }
    __syncthreads();
    int c = 0, sc = 0;
    if (threadIdx.x < SLICE_N) {
        c = cnt[threadIdx.x];
        int lane = threadIdx.x & 63, w = threadIdx.x >> 6;
        sc = c;
        for (int off = 1; off < 64; off <<= 1) { int t = __shfl_up(sc, off); if (lane >= off) sc += t; }
        if (lane == 63) wsum[w] = sc;
    }
    __syncthreads();
    int totale = 0;
    if (threadIdx.x < SLICE_N) {
        int w = threadIdx.x >> 6;
        int add = 0;
        for (int q = 0; q < 7; ++q) if (w > q) add += wsum[q];
        sc += add;
        int v = lo + threadIdx.x;
        if (v < N) { nstart[v] = s * CAP_E + sc - c; ndeg[v] = c; }
    }
    __syncthreads();
    if (threadIdx.x < SLICE_N) cnt[threadIdx.x] = sc - c;   // relative cursor
    __syncthreads();
    for (int r = 0; r < REP; ++r) {
        int q = s * REP + r;
        int start = q * CAP_R, end = gcur[q];
        for (int idx = start + threadIdx.x; idx < end; idx += 1024) {
            unsigned long long a = aux[idx];
            int d = (int)(a & 0x1FFFFu);
            int p = atomicAdd(&cnt[d & (SLICE_N - 1)], 1);
            stage[p] = (unsigned)(a >> 17);
        }
    }
    __syncthreads();
    totale = cnt[SLICE_N - 1];   // after pass B, cnt[last] = excl[last]+count[last] = total
    for (int i = threadIdx.x; i < totale; i += 1024)
        packed[s * CAP_E + i] = stage[i];
}

// Degree-bucket partition of nodes. bin = min(deg, 63).
__global__ __launch_bounds__(256) void dbin_kernel(const int* __restrict__ ndeg, int N,
                                                   int* __restrict__ bcnt, int* __restrict__ bucket) {
    __shared__ int cnt[NBIN];
    __shared__ int base[NBIN];
    if (threadIdx.x < NBIN) cnt[threadIdx.x] = 0;
    __syncthreads();
    int v = blockIdx.x * 256 + threadIdx.x;
    int b = -1, rk = 0;
    if (v < N) { b = min(ndeg[v], NBIN - 1); rk = atomicAdd(&cnt[b], 1); }
    __syncthreads();
    if (threadIdx.x < NBIN && cnt[threadIdx.x] > 0)
        base[threadIdx.x] = atomicAdd(&bcnt[threadIdx.x], cnt[threadIdx.x]);
    __syncthreads();
    if (b >= 0) bucket[b * CAP_B + base[b] + rk] = v;
}

// Compact buckets -> srt[v'] = {edge_start, v | deg<<17}; inline prefix over bcnt.
__global__ void compact_kernel(const int* __restrict__ bucket, const int* __restrict__ bcnt,
                               const int* __restrict__ nstart, const int* __restrict__ ndeg,
                               int2* __restrict__ srt) {
    __shared__ int sbase;
    int b = blockIdx.x;
    if (threadIdx.x == 0) {
        int run = 0;
        for (int i = 0; i < b; ++i) run += bcnt[i];
        sbase = run;
    }
    __syncthreads();
    int n = bcnt[b], base = sbase;
    for (int i = threadIdx.x; i < n; i += 256) {
        int v = bucket[b * CAP_B + i];
        srt[base + i] = make_int2(nstart[v], v | (ndeg[v] << 17));
    }
}

// 8 lanes per node (h8), 32 nodes per block, degree-sorted via srt.
// acc = sum relu(nodearr[src] + tB[ea]); tB in LDS; dot2 epilogue.
template <bool FINAL>
__global__ __launch_bounds__(256, 8) void gather_kernel(
    const unsigned* __restrict__ packed, const int2* __restrict__ srt,
    const _Float16* __restrict__ nodearr, const _Float16* __restrict__ tB,
    const unsigned* __restrict__ wst_g, const _Float16* __restrict__ tAu,
    const int* __restrict__ x, _Float16* __restrict__ out, int N)
{
    __shared__ _Float16 tbs[4 * 64];
    __shared__ unsigned wst[32 * 64];
    __shared__ _Float16 rowb[32][72];
    tbs[threadIdx.x] = tB[threadIdx.x];
    if (!FINAL)
        for (int idx = threadIdx.x; idx < 2048; idx += 256) wst[idx] = wst_g[idx];
    __syncthreads();
    int t = blockIdx.x * 256 + threadIdx.x;
    int vi = t >> 3;
    int j = threadIdx.x & 7;
    int w = threadIdx.x >> 3;
    const h8* na8 = (const h8*)nodearr;
    const _Float16* tbsj = tbs + j * 8;
    h8 acc = {};
    int v = 0;
    bool valid = vi < N;
    if (valid) {
        int2 s2 = srt[vi];
        int e = s2.x;
        v = (int)((unsigned)s2.y & 0x1FFFFu);
        int end = e + (int)((unsigned)s2.y >> 17);
        for (; e + 7 < end; e += 8) {
            unsigned q0 = packed[e],     q1 = packed[e + 1], q2 = packed[e + 2], q3 = packed[e + 3];
            unsigned q4 = packed[e + 4], q5 = packed[e + 5], q6 = packed[e + 6], q7 = packed[e + 7];
            h8 m0 = na8[(q0 & 0x1FFFFu) * 8 + j];
            h8 m1 = na8[(q1 & 0x1FFFFu) * 8 + j];
            h8 m2 = na8[(q2 & 0x1FFFFu) * 8 + j];
            h8 m3 = na8[(q3 & 0x1FFFFu) * 8 + j];
            h8 m4 = na8[(q4 & 0x1FFFFu) * 8 + j];
            h8 m5 = na8[(q5 & 0x1FFFFu) * 8 + j];
            h8 m6 = na8[(q6 & 0x1FFFFu) * 8 + j];
            h8 m7 = na8[(q7 & 0x1FFFFu) * 8 + j];
            h8 t0 = *(const h8*)&tbsj[(q0 >> 17) * 64];
            h8 t1 = *(const h8*)&tbsj[(q1 >> 17) * 64];
            h8 t2 = *(const h8*)&tbsj[(q2 >> 17) * 64];
            h8 t3 = *(const h8*)&tbsj[(q3 >> 17) * 64];
            h8 t4 = *(const h8*)&tbsj[(q4 >> 17) * 64];
            h8 t5 = *(const h8*)&tbsj[(q5 >> 17) * 64];
            h8 t6 = *(const h8*)&tbsj[(q6 >> 17) * 64];
            h8 t7 = *(const h8*)&tbsj[(q7 >> 17) * 64];
            h8 s0 = relu8(m0 + t0), s1 = relu8(m1 + t1);
            h8 s2v = relu8(m2 + t2), s3 = relu8(m3 + t3);
            h8 s4 = relu8(m4 + t4), s5 = relu8(m5 + t5);
            h8 s6 = relu8(m6 + t6), s7 = relu8(m7 + t7);
            acc += ((s0 + s1) + (s2v + s3)) + ((s4 + s5) + (s6 + s7));
        }
        for (; e < end; ++e) {
            unsigned q0 = packed[e];
            h8 m0 = na8[(q0 & 0x1FFFFu) * 8 + j];
            h8 t0 = *(const h8*)&tbsj[(q0 >> 17) * 64];
            acc += relu8(m0 + t0);
        }
    }
    if (FINAL) {
        if (valid) ((h8*)out)[(long long)v * 8 + j] = acc;
        return;
    }
    *(h8*)&rowb[w][j * 8] = acc;
    __syncthreads();
    if (!valid) return;
    const h2* rp = (const h2*)&rowb[w][0];
    const unsigned* wj = wst + j * 8;
    float o0 = 0.f, o1 = 0.f, o2 = 0.f, o3 = 0.f, o4 = 0.f, o5 = 0.f, o6 = 0.f, o7 = 0.f;
#pragma unroll
    for (int k2 = 0; k2 < 32; ++k2) {
        h2 r = rp[k2];
        uint4 wa = *(const uint4*)&wj[k2 * 64];
        uint4 wb = *(const uint4*)&wj[k2 * 64 + 4];
        o0 = __builtin_amdgcn_fdot2(r, u2h(wa.x), o0, false);
        o1 = __builtin_amdgcn_fdot2(r, u2h(wa.y), o1, false);
        o2 = __builtin_amdgcn_fdot2(r, u2h(wa.z), o2, false);
        o3 = __builtin_amdgcn_fdot2(r, u2h(wa.w), o3, false);
        o4 = __builtin_amdgcn_fdot2(r, u2h(wb.x), o4, false);
        o5 = __builtin_amdgcn_fdot2(r, u2h(wb.y), o5, false);
        o6 = __builtin_amdgcn_fdot2(r, u2h(wb.z), o6, false);
        o7 = __builtin_amdgcn_fdot2(r, u2h(wb.w), o7, false);
    }
    h8 ta = ((const h8*)tAu)[x[v] * 8 + j];
    h8 o;
    o[0] = (_Float16)(o0 + (float)ta[0]); o[1] = (_Float16)(o1 + (float)ta[1]);
    o[2] = (_Float16)(o2 + (float)ta[2]); o[3] = (_Float16)(o3 + (float)ta[3]);
    o[4] = (_Float16)(o4 + (float)ta[4]); o[5] = (_Float16)(o5 + (float)ta[5]);
    o[6] = (_Float16)(o6 + (float)ta[6]); o[7] = (_Float16)(o7 + (float)ta[7]);
    ((h8*)out)[(long long)v * 8 + j] = o;
}

// batch is sorted: run-length accumulate, flush on mol change.
__global__ void mol_pool_kernel(const _Float16* __restrict__ ns, const int* __restrict__ batch,
                                float* __restrict__ mol, int N) {
    int g = (blockIdx.x * blockDim.x + threadIdx.x) >> 4;
    int j = threadIdx.x & 15;
    int n0 = g * 32;
    if (n0 >= N) return;
    int n1 = min(n0 + 32, N);
    const h4* ns4 = (const h4*)ns;
    int cur = batch[n0];
    float ax = 0.f, ay = 0.f, az = 0.f, aw = 0.f;
    for (int n = n0; n < n1; ++n) {
        int b = batch[n];
        if (b != cur) {
            float* mp = &mol[(long long)cur * 64 + j * 4];
            atomicAdd(mp + 0, ax); atomicAdd(mp + 1, ay);
            atomicAdd(mp + 2, az); atomicAdd(mp + 3, aw);
            ax = ay = az = aw = 0.f; cur = b;
        }
        h4 vv = ns4[(long long)n * 16 + j];
        ax += (float)vv.x; ay += (float)vv.y; az += (float)vv.z; aw += (float)vv.w;
    }
    float* mp = &mol[(long long)cur * 64 + j * 4];
    atomicAdd(mp + 0, ax); atomicAdd(mp + 1, ay);
    atomicAdd(mp + 2, az); atomicAdd(mp + 3, aw);
}

__global__ void head_kernel(const float* __restrict__ mol, const float* __restrict__ W1,
                            const float* __restrict__ b1, const float* __restrict__ W2,
                            const float* __restrict__ b2, float* __restrict__ out) {
    int g = blockIdx.x;
    int j = threadIdx.x;
    float s = b1[j];
#pragma unroll
    for (int k = 0; k < 64; ++k) s = fmaf(mol[g * 64 + k], W1[k * 128 + j], s);
    s = fmaxf(s, 0.0f) * W2[j];
    __shared__ float red[128];
    red[j] = s;
    __syncthreads();
    for (int off = 64; off > 0; off >>= 1) {
        if (j < off) red[j] += red[j + off];
        __syncthreads();
    }
    if (j == 0) out[g] = red[0] + b2[0];
}

extern "C" void kernel_launch(void* const* d_in, const int* in_sizes, int n_in,
                              void* d_out, int out_size, void* d_ws, size_t ws_size,
                              hipStream_t stream) {
    const int*   x          = (const int*)d_in[0];
    const int*   eattr      = (const int*)d_in[1];
    const int*   ei         = (const int*)d_in[2];
    const int*   batch      = (const int*)d_in[3];
    const float* atom_table = (const float*)d_in[4];
    const float* bond_table = (const float*)d_in[5];
    const float* Wi         = (const float*)d_in[6];
    const float* bi         = (const float*)d_in[7];
    const float* Wu         = (const float*)d_in[8];
    const float* bu         = (const float*)d_in[9];
    const float* W1         = (const float*)d_in[10];
    const float* b1         = (const float*)d_in[11];
    const float* W2         = (const float*)d_in[12];
    const float* b2         = (const float*)d_in[13];

    const int N = in_sizes[0];      // 100000
    const int E = in_sizes[1];      // 1600000
    const int M = out_size;         // 2048
    const int AR = in_sizes[4] / 64;                          // 119 atom rows
    const int K = (N + SLICE_N - 1) >> SLICE_SHIFT;           // 196 slices
    const int ab = (AR * MSG + 255) / 256;                    // 30 blocks per tabA

    char* ws = (char*)d_ws;
    size_t off_b = 0;
    auto alloc = [&](size_t bytes) -> void* {
        void* p = ws + off_b;
        off_b = (off_b + bytes + 255) & ~(size_t)255;
        return p;
    };
    size_t nbytes = (size_t)N * MSG * 2;                 // 12.8 MB
    size_t abytes = (size_t)K * REP * CAP_R * 8;         // 19.3 MB
    _Float16* bufA  = (_Float16*)alloc(nbytes);
    _Float16* bufB  = (_Float16*)alloc(nbytes > abytes ? nbytes : abytes);  // aliased w/ aux
    _Float16* bufC  = (_Float16*)alloc(nbytes);
    unsigned long long* aux = (unsigned long long*)bufB;   // dead before bufB first written
    unsigned* packed = (unsigned*)alloc((size_t)K * CAP_E * 4);   // 9.6 MB
    int*      nstart = (int*)alloc((size_t)N * 4);
    int*      ndeg   = (int*)alloc((size_t)N * 4);
    int2*     srt    = (int2*)alloc((size_t)N * 8);
    int*      bucket = (int*)alloc((size_t)NBIN * CAP_B * 4);
    int*      bcnt   = (int*)alloc((size_t)NBIN * 4);
    int*      gcur   = (int*)alloc((size_t)K * REP * 4);
    _Float16* tAi    = (_Float16*)alloc((size_t)AR * MSG * 2);
    _Float16* tBi    = (_Float16*)alloc((size_t)4 * MSG * 2);
    _Float16* tAu    = (_Float16*)alloc((size_t)AR * MSG * 2);
    _Float16* tBu    = (_Float16*)alloc((size_t)4 * MSG * 2);
    unsigned* wstb   = (unsigned*)alloc((size_t)32 * 64 * 4);
    float*    mol    = (float*)alloc((size_t)M * MSG * 4);
    (void)ws_size; (void)n_in;

    const float* Wagg = Wu + 80 * MSG;

    // ---- fused setup: tables + wst + gcur/bcnt + mol zero ----
    setup_kernel<<<2 * ab + 11 + 128, 256, 0, stream>>>(atom_table, bond_table, Wi, bi, Wu, bu, Wagg,
                                                        tAi, tBi, tAu, tBu, wstb, gcur, bcnt, mol,
                                                        AR, K, ab);
    node_init_kernel<<<(int)(((long long)N * 8 + 255) / 256), 256, 0, stream>>>(x, tAi, bufC, N);

    // ---- CSR by dst: partition (run-staged) -> place (LDS-staged coalesced) ----
    partition_kernel<<<(E + 1023) / 1024, 256, 0, stream>>>(ei, eattr, E, gcur, aux, K);
    place_kernel<<<K, 1024, 0, stream>>>(aux, gcur, nstart, ndeg, packed, N);

    // ---- degree sort: bucket partition -> compact (srt) ----
    dbin_kernel<<<(N + 255) / 256, 256, 0, stream>>>(ndeg, N, bcnt, bucket);
    compact_kernel<<<NBIN, 256, 0, stream>>>(bucket, bcnt, nstart, ndeg, srt);

    // ---- message passes ----
    const int gblocks = (int)(((long long)N * 8 + 255) / 256);
    gather_kernel<false><<<gblocks, 256, 0, stream>>>(packed, srt, bufC, tBi, wstb, tAu, x, bufA, N);
    gather_kernel<false><<<gblocks, 256, 0, stream>>>(packed, srt, bufA, tBu, wstb, tAu, x, bufB, N);
    gather_kernel<false><<<gblocks, 256, 0, stream>>>(packed, srt, bufB, tBu, wstb, tAu, x, bufA, N);
    gather_kernel<false><<<gblocks, 256, 0, stream>>>(packed, srt, bufA, tBu, wstb, tAu, x, bufB, N);
    gather_kernel<true><<<gblocks, 256, 0, stream>>>(packed, srt, bufB, tBu, nullptr, nullptr, nullptr, bufA, N);

    // ---- readout ----
    mol_pool_kernel<<<(((N + 31) / 32) * 16 + 255) / 256, 256, 0, stream>>>(bufA, batch, mol, N);
    head_kernel<<<M, 128, 0, stream>>>(mol, W1, b1, W2, b2, (float*)d_out);
}

// Round 14
// 264.379 us; speedup vs baseline: 1.9544x; 1.0856x over previous
//
#include <hip/hip_runtime.h>

#define MSG 64
#define SLICE_SHIFT 9      // 512 nodes per slice
#define SLICE_N (1 << SLICE_SHIFT)
#define MAXSLICES 256
#define REP 8              // cursor replicas per slice
#define CAP_R 1536         // edges per (slice,rep) aux region (mean 1024)
#define CAP_E 12288        // packed edges per slice (mean 8192, +45 sigma)
#define CAP_B 16384        // nodes per degree bucket
#define NBIN 64

typedef _Float16 h2 __attribute__((ext_vector_type(2)));
typedef _Float16 h4 __attribute__((ext_vector_type(4)));
typedef _Float16 h8 __attribute__((ext_vector_type(8)));

__device__ inline h8 relu8(h8 v) {
    h8 z = {};
    return __builtin_elementwise_max(v, z);
}

__device__ inline h2 u2h(unsigned u) { union { unsigned u; h2 h; } c; c.u = u; return c.h; }

// Fused setup, role-switched on blockIdx:
// [0,ab): tAi  [ab]: tBi  [ab+1,2ab+1): tAu  [2ab+1]: tBu  [2ab+2,2ab+10): wst
// [2ab+10]: gcur + bcnt   [2ab+11, 2ab+11+128): mol zero
__global__ void setup_kernel(const float* __restrict__ atom, const float* __restrict__ bond,
                             const float* __restrict__ Wi, const float* __restrict__ bi,
                             const float* __restrict__ Wu, const float* __restrict__ bu,
                             const float* __restrict__ Wagg,
                             _Float16* __restrict__ tAi, _Float16* __restrict__ tBi,
                             _Float16* __restrict__ tAu, _Float16* __restrict__ tBu,
                             unsigned* __restrict__ wst, int* __restrict__ gcur,
                             int* __restrict__ bcnt, float* __restrict__ mol,
                             int AR, int K, int ab) {
    int b = blockIdx.x;
    if (b < 2 * ab + 2) {
        bool upd = b >= ab + 1;
        const float* W = upd ? Wu : Wi;
        int lb = upd ? b - (ab + 1) : b;
        if (lb < ab) {
            _Float16* tA = upd ? tAu : tAi;
            int t = lb * 256 + threadIdx.x;
            if (t < AR * MSG) {
                int i = t & 63, a = t >> 6;
                float s = 0.f;
                for (int k = 0; k < 64; ++k) s = fmaf(atom[a * 64 + k], W[k * 64 + i], s);
                tA[t] = (_Float16)s;
            }
        } else {
            _Float16* tBo = upd ? tBu : tBi;
            const float* bias = upd ? bu : bi;
            const float* W16 = W + 64 * MSG;
            int t = threadIdx.x;
            int i = t & 63, r = t >> 6;
            float s = bias[i];
            for (int k = 0; k < 16; ++k) s = fmaf(bond[r * 16 + k], W16[k * 64 + i], s);
            tBo[t] = (_Float16)s;
        }
    } else if (b < 2 * ab + 10) {
        int t = (b - (2 * ab + 2)) * 256 + threadIdx.x;
        if (t < 2048) {
            int k2 = t >> 6, c = t & 63;
            h2 h; h[0] = (_Float16)Wagg[(2 * k2) * 64 + c]; h[1] = (_Float16)Wagg[(2 * k2 + 1) * 64 + c];
            union { h2 h; unsigned u; } cv; cv.h = h;
            wst[k2 * 64 + c] = cv.u;
        }
    } else if (b == 2 * ab + 10) {
        for (int q = threadIdx.x; q < K * REP; q += 256) gcur[q] = q * CAP_R;
        if (threadIdx.x < NBIN) bcnt[threadIdx.x] = 0;
    } else {
        int t = (b - (2 * ab + 11)) * 256 + threadIdx.x;   // 128 blocks x 256 x 16B = 512KB
        ((float4*)mol)[t] = make_float4(0.f, 0.f, 0.f, 0.f);
    }
}

// Phase 1: radix-partition with LDS RUN-STAGING for coalesced aux writes.
// record = pw(19b)<<17 | dst(17b), pw = src | eattr<<17.  slice = dst>>9.
__global__ __launch_bounds__(256) void partition_kernel(
    const int* __restrict__ ei, const int* __restrict__ eattr,
    int E, int* __restrict__ gcur, unsigned long long* __restrict__ aux, int K)
{
    __shared__ int cnt[MAXSLICES];
    __shared__ int lexcl[MAXSLICES];
    __shared__ int gbase[MAXSLICES];
    __shared__ int wsum[4];
    __shared__ unsigned long long stage[1024];
    if (threadIdx.x < MAXSLICES) cnt[threadIdx.x] = 0;
    __syncthreads();
    int rep = blockIdx.x & (REP - 1);
    int e0 = blockIdx.x * 1024;
    int total = min(1024, E - e0);
    int sl[4]; int rk[4]; unsigned long long rec[4];
#pragma unroll
    for (int r = 0; r < 4; ++r) {
        sl[r] = -1;
        int e = e0 + r * 256 + threadIdx.x;
        if (e < E) {
            int s = ei[e], d = ei[E + e];
            rec[r] = ((unsigned long long)((unsigned)s | ((unsigned)eattr[e] << 17)) << 17) | (unsigned)d;
            sl[r] = d >> SLICE_SHIFT;
            rk[r] = atomicAdd(&cnt[sl[r]], 1);
        }
    }
    __syncthreads();
    {
        int c = cnt[threadIdx.x];
        int lane = threadIdx.x & 63, w = threadIdx.x >> 6;
        int sc = c;
        for (int off = 1; off < 64; off <<= 1) { int t = __shfl_up(sc, off); if (lane >= off) sc += t; }
        if (lane == 63) wsum[w] = sc;
        __syncthreads();
        int add = 0;
        for (int q = 0; q < 3; ++q) if (w > q) add += wsum[q];
        lexcl[threadIdx.x] = sc + add - c;
        if (threadIdx.x < K && c > 0)
            gbase[threadIdx.x] = atomicAdd(&gcur[threadIdx.x * REP + rep], c);
    }
    __syncthreads();
#pragma unroll
    for (int r = 0; r < 4; ++r)
        if (sl[r] >= 0) stage[lexcl[sl[r]] + rk[r]] = rec[r];
    __syncthreads();
#pragma unroll
    for (int r = 0; r < 4; ++r) {
        int i = r * 256 + threadIdx.x;
        if (i < total) {
            unsigned long long a = stage[i];
            int s = (int)((unsigned)a & 0x1FFFFu) >> SLICE_SHIFT;
            aux[gbase[s] + (i - lexcl[s])] = a;
        }
    }
}

// Phase 2: one block OWNS one slice. Pass A: count + scan -> nstart (+deg).
// Pass B: scatter pw into LDS stage at final relative position.
// Pass C: stream stage out linearly. Pass D: degree-bucket this slice's nodes
// (fused dbin): bucket entry = v | deg<<17.
__global__ __launch_bounds__(1024) void place_kernel(
    const unsigned long long* __restrict__ aux, const int* __restrict__ gcur,
    int* __restrict__ nstart, int* __restrict__ bcnt, int* __restrict__ bucket,
    unsigned* __restrict__ packed, int N)
{
    __shared__ int cnt[SLICE_N];
    __shared__ int wsum[8];
    __shared__ unsigned stage[CAP_E];
    __shared__ int bc[NBIN];
    __shared__ int bb[NBIN];
    int s = blockIdx.x;
    int lo = s << SLICE_SHIFT;
    if (threadIdx.x < SLICE_N) cnt[threadIdx.x] = 0;
    if (threadIdx.x >= SLICE_N && threadIdx.x < SLICE_N + NBIN) bc[threadIdx.x - SLICE_N] = 0;
    __syncthreads();
    for (int r = 0; r < REP; ++r) {
        int q = s * REP + r;
        int start = q * CAP_R, end = gcur[q];
        for (int idx = start + threadIdx.x; idx < end; idx += 1024)
            atomicAdd(&cnt[(int)(aux[idx] & 0x1FFFFu) & (SLICE_N - 1)], 1);
    }
    __syncthreads();
    int c = 0, sc = 0;
    if (threadIdx.x < SLICE_N) {
        c = cnt[threadIdx.x];
        int lane = threadIdx.x & 63, w = threadIdx.x >> 6;
        sc = c;
        for (int off = 1; off < 64; off <<= 1) { int t = __shfl_up(sc, off); if (lane >= off) sc += t; }
        if (lane == 63) wsum[w] = sc;
    }
    __syncthreads();
    int v = lo + threadIdx.x;
    int bin = -1, rk = 0;
    if (threadIdx.x < SLICE_N) {
        int w = threadIdx.x >> 6;
        int add = 0;
        for (int q = 0; q < 7; ++q) if (w > q) add += wsum[q];
        sc += add;
        if (v < N) {
            nstart[v] = s * CAP_E + sc - c;
            bin = min(c, NBIN - 1);
            rk = atomicAdd(&bc[bin], 1);
        }
    }
    __syncthreads();
    if (threadIdx.x < NBIN && bc[threadIdx.x] > 0)
        bb[threadIdx.x] = atomicAdd(&bcnt[threadIdx.x], bc[threadIdx.x]);
    __syncthreads();
    if (bin >= 0) bucket[bin * CAP_B + bb[bin] + rk] = v | (c << 17);
    if (threadIdx.x < SLICE_N) cnt[threadIdx.x] = sc - c;   // relative cursor
    __syncthreads();
    for (int r = 0; r < REP; ++r) {
        int q = s * REP + r;
        int start = q * CAP_R, end = gcur[q];
        for (int idx = start + threadIdx.x; idx < end; idx += 1024) {
            unsigned long long a = aux[idx];
            int d = (int)(a & 0x1FFFFu);
            int p = atomicAdd(&cnt[d & (SLICE_N - 1)], 1);
            stage[p] = (unsigned)(a >> 17);
        }
    }
    __syncthreads();
    int totale = cnt[SLICE_N - 1];
    for (int i = threadIdx.x; i < totale; i += 1024)
        packed[s * CAP_E + i] = stage[i];
}

// Compact buckets -> srt[v'] = {edge_start, v | deg<<17}; inline prefix over bcnt.
__global__ void compact_kernel(const int* __restrict__ bucket, const int* __restrict__ bcnt,
                               const int* __restrict__ nstart, int2* __restrict__ srt) {
    __shared__ int sbase;
    int b = blockIdx.x;
    if (threadIdx.x == 0) {
        int run = 0;
        for (int i = 0; i < b; ++i) run += bcnt[i];
        sbase = run;
    }
    __syncthreads();
    int n = bcnt[b], base = sbase;
    for (int i = threadIdx.x; i < n; i += 256) {
        int e = bucket[b * CAP_B + i];
        int v = e & 0x1FFFF;
        srt[base + i] = make_int2(nstart[v], e);
    }
}

// 8 lanes per node (h8), 32 nodes per block, degree-sorted via srt.
// MODE 0 (pass 0): per edge read x[src] (L2-hit, 400KB ws) + tAi[x[src]] row
//   (L1-hit, 15KB) — no 12.8MB materialized bufC.
// MODE 1 (mid): per edge read nodearr[src] (128B random).
// MODE 2 (final): as 1, raw acc out.
// tB in 512B LDS; dot2 epilogue (+ tAu[x[v]]) for MODE 0/1.
template <int MODE>
__global__ __launch_bounds__(256, 8) void gather_kernel(
    const unsigned* __restrict__ packed, const int2* __restrict__ srt,
    const _Float16* __restrict__ nodearr, const _Float16* __restrict__ tB,
    const unsigned* __restrict__ wst_g, const _Float16* __restrict__ tAu,
    const int* __restrict__ x, const _Float16* __restrict__ tAi,
    _Float16* __restrict__ out, int N)
{
    __shared__ _Float16 tbs[4 * 64];
    __shared__ unsigned wst[32 * 64];
    __shared__ _Float16 rowb[32][72];
    tbs[threadIdx.x] = tB[threadIdx.x];
    if (MODE != 2)
        for (int idx = threadIdx.x; idx < 2048; idx += 256) wst[idx] = wst_g[idx];
    __syncthreads();
    int t = blockIdx.x * 256 + threadIdx.x;
    int vi = t >> 3;
    int j = threadIdx.x & 7;
    int w = threadIdx.x >> 3;
    const h8* na8 = (const h8*)nodearr;
    const h8* tAi8 = (const h8*)tAi;
    const _Float16* tbsj = tbs + j * 8;
    h8 acc = {};
    int v = 0;
    bool valid = vi < N;
    if (valid) {
        int2 s2 = srt[vi];
        int e = s2.x;
        v = (int)((unsigned)s2.y & 0x1FFFFu);
        int end = e + (int)((unsigned)s2.y >> 17);
        for (; e + 7 < end; e += 8) {
            unsigned q0 = packed[e],     q1 = packed[e + 1], q2 = packed[e + 2], q3 = packed[e + 3];
            unsigned q4 = packed[e + 4], q5 = packed[e + 5], q6 = packed[e + 6], q7 = packed[e + 7];
            h8 m0, m1, m2, m3, m4, m5, m6, m7;
            if (MODE == 0) {
                m0 = tAi8[(long long)x[q0 & 0x1FFFFu] * 8 + j];
                m1 = tAi8[(long long)x[q1 & 0x1FFFFu] * 8 + j];
                m2 = tAi8[(long long)x[q2 & 0x1FFFFu] * 8 + j];
                m3 = tAi8[(long long)x[q3 & 0x1FFFFu] * 8 + j];
                m4 = tAi8[(long long)x[q4 & 0x1FFFFu] * 8 + j];
                m5 = tAi8[(long long)x[q5 & 0x1FFFFu] * 8 + j];
                m6 = tAi8[(long long)x[q6 & 0x1FFFFu] * 8 + j];
                m7 = tAi8[(long long)x[q7 & 0x1FFFFu] * 8 + j];
            } else {
                m0 = na8[(q0 & 0x1FFFFu) * 8 + j];
                m1 = na8[(q1 & 0x1FFFFu) * 8 + j];
                m2 = na8[(q2 & 0x1FFFFu) * 8 + j];
                m3 = na8[(q3 & 0x1FFFFu) * 8 + j];
                m4 = na8[(q4 & 0x1FFFFu) * 8 + j];
                m5 = na8[(q5 & 0x1FFFFu) * 8 + j];
                m6 = na8[(q6 & 0x1FFFFu) * 8 + j];
                m7 = na8[(q7 & 0x1FFFFu) * 8 + j];
            }
            h8 t0 = *(const h8*)&tbsj[(q0 >> 17) * 64];
            h8 t1 = *(const h8*)&tbsj[(q1 >> 17) * 64];
            h8 t2 = *(const h8*)&tbsj[(q2 >> 17) * 64];
            h8 t3 = *(const h8*)&tbsj[(q3 >> 17) * 64];
            h8 t4 = *(const h8*)&tbsj[(q4 >> 17) * 64];
            h8 t5 = *(const h8*)&tbsj[(q5 >> 17) * 64];
            h8 t6 = *(const h8*)&tbsj[(q6 >> 17) * 64];
            h8 t7 = *(const h8*)&tbsj[(q7 >> 17) * 64];
            h8 s0 = relu8(m0 + t0), s1 = relu8(m1 + t1);
            h8 s2v = relu8(m2 + t2), s3 = relu8(m3 + t3);
            h8 s4 = relu8(m4 + t4), s5 = relu8(m5 + t5);
            h8 s6 = relu8(m6 + t6), s7 = relu8(m7 + t7);
            acc += ((s0 + s1) + (s2v + s3)) + ((s4 + s5) + (s6 + s7));
        }
        for (; e < end; ++e) {
            unsigned q0 = packed[e];
            h8 m0;
            if (MODE == 0) m0 = tAi8[(long long)x[q0 & 0x1FFFFu] * 8 + j];
            else           m0 = na8[(q0 & 0x1FFFFu) * 8 + j];
            h8 t0 = *(const h8*)&tbsj[(q0 >> 17) * 64];
            acc += relu8(m0 + t0);
        }
    }
    if (MODE == 2) {
        if (valid) ((h8*)out)[(long long)v * 8 + j] = acc;
        return;
    }
    *(h8*)&rowb[w][j * 8] = acc;
    __syncthreads();
    if (!valid) return;
    const h2* rp = (const h2*)&rowb[w][0];
    const unsigned* wj = wst + j * 8;
    float o0 = 0.f, o1 = 0.f, o2 = 0.f, o3 = 0.f, o4 = 0.f, o5 = 0.f, o6 = 0.f, o7 = 0.f;
#pragma unroll
    for (int k2 = 0; k2 < 32; ++k2) {
        h2 r = rp[k2];
        uint4 wa = *(const uint4*)&wj[k2 * 64];
        uint4 wb = *(const uint4*)&wj[k2 * 64 + 4];
        o0 = __builtin_amdgcn_fdot2(r, u2h(wa.x), o0, false);
        o1 = __builtin_amdgcn_fdot2(r, u2h(wa.y), o1, false);
        o2 = __builtin_amdgcn_fdot2(r, u2h(wa.z), o2, false);
        o3 = __builtin_amdgcn_fdot2(r, u2h(wa.w), o3, false);
        o4 = __builtin_amdgcn_fdot2(r, u2h(wb.x), o4, false);
        o5 = __builtin_amdgcn_fdot2(r, u2h(wb.y), o5, false);
        o6 = __builtin_amdgcn_fdot2(r, u2h(wb.z), o6, false);
        o7 = __builtin_amdgcn_fdot2(r, u2h(wb.w), o7, false);
    }
    h8 ta = ((const h8*)tAu)[x[v] * 8 + j];
    h8 o;
    o[0] = (_Float16)(o0 + (float)ta[0]); o[1] = (_Float16)(o1 + (float)ta[1]);
    o[2] = (_Float16)(o2 + (float)ta[2]); o[3] = (_Float16)(o3 + (float)ta[3]);
    o[4] = (_Float16)(o4 + (float)ta[4]); o[5] = (_Float16)(o5 + (float)ta[5]);
    o[6] = (_Float16)(o6 + (float)ta[6]); o[7] = (_Float16)(o7 + (float)ta[7]);
    ((h8*)out)[(long long)v * 8 + j] = o;
}

// batch is sorted: run-length accumulate, flush on mol change.
__global__ void mol_pool_kernel(const _Float16* __restrict__ ns, const int* __restrict__ batch,
                                float* __restrict__ mol, int N) {
    int g = (blockIdx.x * blockDim.x + threadIdx.x) >> 4;
    int j = threadIdx.x & 15;
    int n0 = g * 32;
    if (n0 >= N) return;
    int n1 = min(n0 + 32, N);
    const h4* ns4 = (const h4*)ns;
    int cur = batch[n0];
    float ax = 0.f, ay = 0.f, az = 0.f, aw = 0.f;
    for (int n = n0; n < n1; ++n) {
        int b = batch[n];
        if (b != cur) {
            float* mp = &mol[(long long)cur * 64 + j * 4];
            atomicAdd(mp + 0, ax); atomicAdd(mp + 1, ay);
            atomicAdd(mp + 2, az); atomicAdd(mp + 3, aw);
            ax = ay = az = aw = 0.f; cur = b;
        }
        h4 vv = ns4[(long long)n * 16 + j];
        ax += (float)vv.x; ay += (float)vv.y; az += (float)vv.z; aw += (float)vv.w;
    }
    float* mp = &mol[(long long)cur * 64 + j * 4];
    atomicAdd(mp + 0, ax); atomicAdd(mp + 1, ay);
    atomicAdd(mp + 2, az); atomicAdd(mp + 3, aw);
}

__global__ void head_kernel(const float* __restrict__ mol, const float* __restrict__ W1,
                            const float* __restrict__ b1, const float* __restrict__ W2,
                            const float* __restrict__ b2, float* __restrict__ out) {
    int g = blockIdx.x;
    int j = threadIdx.x;
    float s = b1[j];
#pragma unroll
    for (int k = 0; k < 64; ++k) s = fmaf(mol[g * 64 + k], W1[k * 128 + j], s);
    s = fmaxf(s, 0.0f) * W2[j];
    __shared__ float red[128];
    red[j] = s;
    __syncthreads();
    for (int off = 64; off > 0; off >>= 1) {
        if (j < off) red[j] += red[j + off];
        __syncthreads();
    }
    if (j == 0) out[g] = red[0] + b2[0];
}

extern "C" void kernel_launch(void* const* d_in, const int* in_sizes, int n_in,
                              void* d_out, int out_size, void* d_ws, size_t ws_size,
                              hipStream_t stream) {
    const int*   x          = (const int*)d_in[0];
    const int*   eattr      = (const int*)d_in[1];
    const int*   ei         = (const int*)d_in[2];
    const int*   batch      = (const int*)d_in[3];
    const float* atom_table = (const float*)d_in[4];
    const float* bond_table = (const float*)d_in[5];
    const float* Wi         = (const float*)d_in[6];
    const float* bi         = (const float*)d_in[7];
    const float* Wu         = (const float*)d_in[8];
    const float* bu         = (const float*)d_in[9];
    const float* W1         = (const float*)d_in[10];
    const float* b1         = (const float*)d_in[11];
    const float* W2         = (const float*)d_in[12];
    const float* b2         = (const float*)d_in[13];

    const int N = in_sizes[0];      // 100000
    const int E = in_sizes[1];      // 1600000
    const int M = out_size;         // 2048
    const int AR = in_sizes[4] / 64;                          // 119 atom rows
    const int K = (N + SLICE_N - 1) >> SLICE_SHIFT;           // 196 slices
    const int ab = (AR * MSG + 255) / 256;                    // 30 blocks per tabA

    char* ws = (char*)d_ws;
    size_t off_b = 0;
    auto alloc = [&](size_t bytes) -> void* {
        void* p = ws + off_b;
        off_b = (off_b + bytes + 255) & ~(size_t)255;
        return p;
    };
    size_t nbytes = (size_t)N * MSG * 2;                 // 12.8 MB
    size_t abytes = (size_t)K * REP * CAP_R * 8;         // 19.3 MB
    _Float16* bufA  = (_Float16*)alloc(nbytes);
    _Float16* bufB  = (_Float16*)alloc(nbytes > abytes ? nbytes : abytes);  // aliased w/ aux
    unsigned long long* aux = (unsigned long long*)bufB;   // dead before bufB first written
    unsigned* packed = (unsigned*)alloc((size_t)K * CAP_E * 4);   // 9.6 MB
    int*      nstart = (int*)alloc((size_t)N * 4);
    int2*     srt    = (int2*)alloc((size_t)N * 8);
    int*      bucket = (int*)alloc((size_t)NBIN * CAP_B * 4);
    int*      bcnt   = (int*)alloc((size_t)NBIN * 4);
    int*      gcur   = (int*)alloc((size_t)K * REP * 4);
    _Float16* tAi    = (_Float16*)alloc((size_t)AR * MSG * 2);
    _Float16* tBi    = (_Float16*)alloc((size_t)4 * MSG * 2);
    _Float16* tAu    = (_Float16*)alloc((size_t)AR * MSG * 2);
    _Float16* tBu    = (_Float16*)alloc((size_t)4 * MSG * 2);
    unsigned* wstb   = (unsigned*)alloc((size_t)32 * 64 * 4);
    float*    mol    = (float*)alloc((size_t)M * MSG * 4);
    (void)ws_size; (void)n_in;

    const float* Wagg = Wu + 80 * MSG;

    // ---- fused setup: tables + wst + gcur/bcnt + mol zero ----
    setup_kernel<<<2 * ab + 11 + 128, 256, 0, stream>>>(atom_table, bond_table, Wi, bi, Wu, bu, Wagg,
                                                        tAi, tBi, tAu, tBu, wstb, gcur, bcnt, mol,
                                                        AR, K, ab);

    // ---- CSR by dst: partition (run-staged) -> place (LDS-staged + fused dbin) ----
    partition_kernel<<<(E + 1023) / 1024, 256, 0, stream>>>(ei, eattr, E, gcur, aux, K);
    place_kernel<<<K, 1024, 0, stream>>>(aux, gcur, nstart, bcnt, bucket, packed, N);
    compact_kernel<<<NBIN, 256, 0, stream>>>(bucket, bcnt, nstart, srt);

    // ---- message passes: pass 0 reads x/tAi directly (no bufC) ----
    const int gblocks = (int)(((long long)N * 8 + 255) / 256);
    gather_kernel<0><<<gblocks, 256, 0, stream>>>(packed, srt, nullptr, tBi, wstb, tAu, x, tAi, bufA, N);
    gather_kernel<1><<<gblocks, 256, 0, stream>>>(packed, srt, bufA, tBu, wstb, tAu, x, nullptr, bufB, N);
    gather_kernel<1><<<gblocks, 256, 0, stream>>>(packed, srt, bufB, tBu, wstb, tAu, x, nullptr, bufA, N);
    gather_kernel<1><<<gblocks, 256, 0, stream>>>(packed, srt, bufA, tBu, wstb, tAu, x, nullptr, bufB, N);
    gather_kernel<2><<<gblocks, 256, 0, stream>>>(packed, srt, bufB, tBu, nullptr, nullptr, nullptr, nullptr, bufA, N);

    // ---- readout ----
    mol_pool_kernel<<<(((N + 31) / 32) * 16 + 255) / 256, 256, 0, stream>>>(bufA, batch, mol, N);
    head_kernel<<<M, 128, 0, stream>>>(mol, W1, b1, W2, b2, (float*)d_out);
}